// Round 8
// baseline (883.903 us; speedup 1.0000x reference)
//
#include <hip/hip_runtime.h>
#include <math.h>

// ---------------------------------------------------------------------------
// HGT transformer layer. N=50000, D=128, H=8, DH=16, E=300000 per edge type.
// R5: CSR + fused online-softmax aggregation (5000 -> 872 us).
// R7: 128x128 double-buffered fp32 GEMM (GEMMs were ~650 us at ~30 TF).
// ---------------------------------------------------------------------------

__device__ __forceinline__ float gelu_exact(float x) {
    return 0.5f * x * (1.0f + erff(x * 0.70710678118654752f));
}

// --------------------------- LayerNorm (rows of 128) -----------------------
__global__ __launch_bounds__(256) void ln_kernel(
    const float* __restrict__ x, const float* __restrict__ g,
    const float* __restrict__ b, float* __restrict__ out, int nrows)
{
    int row  = (int)((blockIdx.x * 256 + threadIdx.x) >> 6);
    int lane = threadIdx.x & 63;
    if (row >= nrows) return;
    float2 xv = *(const float2*)&x[(size_t)row * 128 + lane * 2];
    float s = xv.x + xv.y;
#pragma unroll
    for (int off = 32; off >= 1; off >>= 1) s += __shfl_xor(s, off, 64);
    float mu = s * (1.0f / 128.0f);
    float d0 = xv.x - mu, d1 = xv.y - mu;
    float v = d0 * d0 + d1 * d1;
#pragma unroll
    for (int off = 32; off >= 1; off >>= 1) v += __shfl_xor(v, off, 64);
    float rs = rsqrtf(v * (1.0f / 128.0f) + 1e-5f);
    float2 gv = *(const float2*)&g[lane * 2];
    float2 bv = *(const float2*)&b[lane * 2];
    float2 o;
    o.x = d0 * rs * gv.x + bv.x;
    o.y = d1 * rs * gv.y + bv.y;
    *(float2*)&out[(size_t)row * 128 + lane * 2] = o;
}

// ------------------ fp32 GEMM, 128x128 tile, double-buffered ---------------
// C[M,N] = A[M,K] @ B[K,N] (+bias), epilogues:
//   0: +bias   1: gelu(+bias)   2: aux1 + s*(acc+bias) + (1-s)*aux2   3: aux1+acc+bias
// 256 threads; per-thread 8x8 = (2x4 rows) x (2x4 cols); BK=16.
// LDS rows padded to 132 floats: fragment reads <=2-way conflicts (free),
// staging writes 2-way. One __syncthreads per K-step (write next buf is safe).
// Requires: N % 128 == 0, K % 16 == 0.
template <int EPI>
__global__ __launch_bounds__(256) void gemm128(
    const float* __restrict__ A, const float* __restrict__ B,
    const float* __restrict__ bias, float* __restrict__ C,
    int M, int N, int K,
    const float* __restrict__ aux1, const float* __restrict__ aux2,
    const float* __restrict__ skipp)
{
    const int LDT = 132;
    __shared__ __align__(16) float As[2][16 * 132];
    __shared__ __align__(16) float Bs[2][16 * 132];
    const int t  = threadIdx.x;
    const int bm = blockIdx.x * 128;
    const int bn = blockIdx.y * 128;
    const int tx = t & 15, ty = t >> 4;

    // staging coords
    const int ar0 = t >> 2;            // A rows: ar0, ar0+64
    const int akc = (t & 3) << 2;      // A k-chunk 0/4/8/12
    const int br  = t >> 5;            // B k-rows: br, br+8
    const int bnc = (t & 31) << 2;     // B col-chunk

    float acc[2][2][4][4] = {};
    float4 ra0, ra1, rb0, rb1;
    const float4 zero4 = make_float4(0.f, 0.f, 0.f, 0.f);

    // prologue: load tile k0=0 into regs
    {
        int g0 = bm + ar0, g1 = g0 + 64;
        ra0 = (g0 < M) ? *(const float4*)&A[(size_t)g0 * K + akc] : zero4;
        ra1 = (g1 < M) ? *(const float4*)&A[(size_t)g1 * K + akc] : zero4;
        rb0 = *(const float4*)&B[(size_t)br * N + bn + bnc];
        rb1 = *(const float4*)&B[(size_t)(br + 8) * N + bn + bnc];
    }

    int buf = 0;
    for (int k0 = 0; k0 < K; k0 += 16) {
        // stage regs -> LDS[buf]
        {
            float* Ab = &As[buf][0];
            Ab[(akc + 0) * LDT + ar0] = ra0.x;
            Ab[(akc + 1) * LDT + ar0] = ra0.y;
            Ab[(akc + 2) * LDT + ar0] = ra0.z;
            Ab[(akc + 3) * LDT + ar0] = ra0.w;
            Ab[(akc + 0) * LDT + ar0 + 64] = ra1.x;
            Ab[(akc + 1) * LDT + ar0 + 64] = ra1.y;
            Ab[(akc + 2) * LDT + ar0 + 64] = ra1.z;
            Ab[(akc + 3) * LDT + ar0 + 64] = ra1.w;
            float* Bb = &Bs[buf][0];
            *(float4*)&Bb[br * LDT + bnc] = rb0;
            *(float4*)&Bb[(br + 8) * LDT + bnc] = rb1;
        }
        __syncthreads();

        // prefetch next tile into regs (overlaps with compute below)
        if (k0 + 16 < K) {
            int g0 = bm + ar0, g1 = g0 + 64;
            int kn = k0 + 16;
            ra0 = (g0 < M) ? *(const float4*)&A[(size_t)g0 * K + kn + akc] : zero4;
            ra1 = (g1 < M) ? *(const float4*)&A[(size_t)g1 * K + kn + akc] : zero4;
            rb0 = *(const float4*)&B[(size_t)(kn + br) * N + bn + bnc];
            rb1 = *(const float4*)&B[(size_t)(kn + br + 8) * N + bn + bnc];
        }

        const float* Ab = &As[buf][0];
        const float* Bb = &Bs[buf][0];
#pragma unroll
        for (int kk = 0; kk < 16; ++kk) {
            float4 a0 = *(const float4*)&Ab[kk * LDT + (ty << 2)];
            float4 a1 = *(const float4*)&Ab[kk * LDT + 64 + (ty << 2)];
            float4 b0 = *(const float4*)&Bb[kk * LDT + (tx << 2)];
            float4 b1 = *(const float4*)&Bb[kk * LDT + 64 + (tx << 2)];
            const float av[8] = {a0.x, a0.y, a0.z, a0.w, a1.x, a1.y, a1.z, a1.w};
            const float bv[8] = {b0.x, b0.y, b0.z, b0.w, b1.x, b1.y, b1.z, b1.w};
#pragma unroll
            for (int mi = 0; mi < 2; ++mi)
#pragma unroll
                for (int i = 0; i < 4; ++i)
#pragma unroll
                    for (int ni = 0; ni < 2; ++ni)
#pragma unroll
                        for (int j = 0; j < 4; ++j)
                            acc[mi][ni][i][j] += av[mi * 4 + i] * bv[ni * 4 + j];
        }
        buf ^= 1;
    }

    float s = 0.0f;
    if (EPI == 2) s = 1.0f / (1.0f + expf(-skipp[0]));
    float bbv[2][4];
    {
        float4 b0 = *(const float4*)&bias[bn + (tx << 2)];
        float4 b1 = *(const float4*)&bias[bn + 64 + (tx << 2)];
        bbv[0][0] = b0.x; bbv[0][1] = b0.y; bbv[0][2] = b0.z; bbv[0][3] = b0.w;
        bbv[1][0] = b1.x; bbv[1][1] = b1.y; bbv[1][2] = b1.z; bbv[1][3] = b1.w;
    }

#pragma unroll
    for (int mi = 0; mi < 2; ++mi)
#pragma unroll
        for (int i = 0; i < 4; ++i) {
            int r = bm + mi * 64 + (ty << 2) + i;
            if (r >= M) continue;
#pragma unroll
            for (int ni = 0; ni < 2; ++ni) {
                size_t cidx = (size_t)r * N + bn + ni * 64 + (tx << 2);
                float o[4];
#pragma unroll
                for (int j = 0; j < 4; ++j) {
                    float v = acc[mi][ni][i][j] + bbv[ni][j];
                    if (EPI == 1) v = gelu_exact(v);
                    o[j] = v;
                }
                if (EPI == 2) {
                    float4 a1 = *(const float4*)&aux1[cidx];
                    float4 a2 = *(const float4*)&aux2[cidx];
                    o[0] = a1.x + s * o[0] + (1.f - s) * a2.x;
                    o[1] = a1.y + s * o[1] + (1.f - s) * a2.y;
                    o[2] = a1.z + s * o[2] + (1.f - s) * a2.z;
                    o[3] = a1.w + s * o[3] + (1.f - s) * a2.w;
                } else if (EPI == 3) {
                    float4 a1 = *(const float4*)&aux1[cidx];
                    o[0] += a1.x; o[1] += a1.y; o[2] += a1.z; o[3] += a1.w;
                }
                *(float4*)&C[cidx] = make_float4(o[0], o[1], o[2], o[3]);
            }
        }
}

// ------------------- per-node relation transforms --------------------------
__global__ __launch_bounds__(256) void rel_transform(
    const float* __restrict__ kqv,
    const float* __restrict__ a_f, const float* __restrict__ m_f,
    const float* __restrict__ a_g, const float* __restrict__ m_g,
    float* __restrict__ kAf, float* __restrict__ kAg,
    float* __restrict__ vMf, float* __restrict__ vMg, int nnodes)
{
    __shared__ float sAf[8 * 16 * 17], sMf[8 * 16 * 17];
    __shared__ float sAg[8 * 16 * 17], sMg[8 * 16 * 17];
    for (int i = threadIdx.x; i < 2048; i += 256) {
        int o = (i >> 4) * 17 + (i & 15);
        sAf[o] = a_f[i]; sMf[o] = m_f[i];
        sAg[o] = a_g[i]; sMg[o] = m_g[i];
    }
    __syncthreads();
    int t = threadIdx.x;
    int f = t & 15, h = (t >> 4) & 7, nl = t >> 7;
    int n = blockIdx.x * 2 + nl;
    if (n >= nnodes) return;
    const float* kp = &kqv[(size_t)n * 384 + h * 16];
    const float* vp = kp + 256;
    float kd[16], vd[16];
#pragma unroll
    for (int i4 = 0; i4 < 4; ++i4) {
        float4 k4 = *(const float4*)&kp[i4 * 4];
        float4 v4 = *(const float4*)&vp[i4 * 4];
        kd[i4 * 4 + 0] = k4.x; kd[i4 * 4 + 1] = k4.y;
        kd[i4 * 4 + 2] = k4.z; kd[i4 * 4 + 3] = k4.w;
        vd[i4 * 4 + 0] = v4.x; vd[i4 * 4 + 1] = v4.y;
        vd[i4 * 4 + 2] = v4.z; vd[i4 * 4 + 3] = v4.w;
    }
    float rkf = 0.f, rkg = 0.f, rvf = 0.f, rvg = 0.f;
#pragma unroll
    for (int d = 0; d < 16; ++d) {
        int idx = (h * 16 + d) * 17 + f;
        rkf += kd[d] * sAf[idx];
        rkg += kd[d] * sAg[idx];
        rvf += vd[d] * sMf[idx];
        rvg += vd[d] * sMg[idx];
    }
    size_t o = (size_t)n * 128 + h * 16 + f;
    kAf[o] = rkf; kAg[o] = rkg; vMf[o] = rvf; vMg[o] = rvg;
}

// -------------------- CSR build ---------------------------------------------
__global__ __launch_bounds__(256) void zero_deg(int* __restrict__ deg, int n) {
    int i = blockIdx.x * 256 + threadIdx.x;
    if (i < n) deg[i] = 0;
}

__global__ __launch_bounds__(256) void count_deg(
    const int* __restrict__ edge, int E, int* __restrict__ deg)
{
    int e = blockIdx.x * 256 + threadIdx.x;
    if (e >= E) return;
    atomicAdd(&deg[edge[E + e]], 1);
}

// single-block 2-level exclusive scan: deg[n] -> rowptr[n+1], cursor[n]
__global__ __launch_bounds__(1024) void scan_kernel(
    const int* __restrict__ deg, int* __restrict__ rowptr,
    int* __restrict__ cursor, int n)
{
    const int tid = threadIdx.x;
    const int CH = (n + 1023) / 1024;
    int beg = tid * CH, end = min(beg + CH, n);
    int s = 0;
    for (int i = beg; i < end; ++i) s += deg[i];
    __shared__ int tmp[1024];
    tmp[tid] = s;
    __syncthreads();
    for (int off = 1; off < 1024; off <<= 1) {
        int t = (tid >= off) ? tmp[tid - off] : 0;
        __syncthreads();
        tmp[tid] += t;
        __syncthreads();
    }
    int run = tmp[tid] - s;  // exclusive prefix of this chunk
    for (int i = beg; i < end; ++i) {
        int d = deg[i];
        rowptr[i] = run;
        cursor[i] = run;
        run += d;
    }
    if (tid == 1023) rowptr[n] = run;
}

__global__ __launch_bounds__(256) void fill_csr(
    const int* __restrict__ edge, int E, unsigned int typebit,
    int* __restrict__ cursor, unsigned int* __restrict__ col)
{
    int e = blockIdx.x * 256 + threadIdx.x;
    if (e >= E) return;
    int src = edge[e], dst = edge[E + e];
    int pos = atomicAdd(&cursor[dst], 1);
    col[pos] = (unsigned int)src | (typebit << 31);
}

// -------------------- fused gather + online softmax + gelu -----------------
__global__ __launch_bounds__(256) void fused_agg(
    const int* __restrict__ rowptr, const unsigned int* __restrict__ col,
    const float* __restrict__ kqv,
    const float* __restrict__ kAf, const float* __restrict__ kAg,
    const float* __restrict__ vMf, const float* __restrict__ vMg,
    const float* __restrict__ p_f, const float* __restrict__ p_g,
    float* __restrict__ outg, int nnodes)
{
    int task = blockIdx.x * 16 + (threadIdx.x >> 4);
    int f    = threadIdx.x & 15;
    if (task >= nnodes * 8) return;
    int dst = task >> 3, h = task & 7;
    const int foff = h * 16 + f;
    float q  = kqv[(size_t)dst * 384 + 128 + foff];
    float pf = p_f[h] * 0.25f;   // p / sqrt(DH)
    float pg = p_g[h] * 0.25f;
    int i = rowptr[dst], end = rowptr[dst + 1];
    float m = -1e30f, s = 0.f, o = 0.f;
    for (; i < end; ++i) {
        unsigned int c = col[i];
        int src = (int)(c & 0x7fffffffu);
        bool tg = (c >> 31) != 0u;
        size_t boff = (size_t)src * 128 + foff;
        float kv = tg ? kAg[boff] : kAf[boff];
        float part = q * kv;
        part += __shfl_xor(part, 1, 16);
        part += __shfl_xor(part, 2, 16);
        part += __shfl_xor(part, 4, 16);
        part += __shfl_xor(part, 8, 16);
        float logit = part * (tg ? pg : pf);
        float mn    = fmaxf(m, logit);
        float scale = expf(m - mn);
        float ev    = expf(logit - mn);
        float vv = tg ? vMg[boff] : vMf[boff];
        s = s * scale + ev;
        o = o * scale + ev * vv;
        m = mn;
    }
    float r = o / (s + 1e-16f);
    outg[(size_t)dst * 128 + foff] = gelu_exact(r);
}

// ---------------------------------------------------------------------------
extern "C" void kernel_launch(void* const* d_in, const int* in_sizes, int n_in,
                              void* d_out, int out_size, void* d_ws, size_t ws_size,
                              hipStream_t stream)
{
    const float* x     = (const float*)d_in[0];
    const int*   ef    = (const int*)d_in[1];
    const int*   eg    = (const int*)d_in[2];
    const float* kqv_w = (const float*)d_in[3];
    const float* kqv_b = (const float*)d_in[4];
    const float* a_f   = (const float*)d_in[5];
    const float* m_f   = (const float*)d_in[6];
    const float* p_f   = (const float*)d_in[7];
    const float* a_g   = (const float*)d_in[8];
    const float* m_g   = (const float*)d_in[9];
    const float* p_g   = (const float*)d_in[10];
    const float* out_w = (const float*)d_in[11];
    const float* out_b = (const float*)d_in[12];
    const float* skip  = (const float*)d_in[13];
    const float* ln1_g = (const float*)d_in[14];
    const float* ln1_b = (const float*)d_in[15];
    const float* ln2_g = (const float*)d_in[16];
    const float* ln2_b = (const float*)d_in[17];
    const float* w1    = (const float*)d_in[18];
    const float* b1    = (const float*)d_in[19];
    const float* w2    = (const float*)d_in[20];
    const float* b2    = (const float*)d_in[21];
    float* out = (float*)d_out;

    const int D  = 128;
    const int Nn = in_sizes[0] / D;   // 50000
    const int E1 = in_sizes[1] / 2;   // 300000
    const int E2 = in_sizes[2] / 2;   // 300000

    // ---- workspace: 9*ND floats + (3N+1+2E) ints. Overlays as before.
    float* ws = (float*)d_ws;
    size_t ND = (size_t)Nn * D;
    float* xn   = ws;             // [ND]
    float* kqvb = xn + ND;        // [3*ND] k|q|v
    float* kAf  = kqvb + 3 * ND;  // [ND]
    float* kAg  = kAf + ND;       // [ND]
    float* vMf  = kAg + ND;       // [ND]
    float* vMg  = vMf + ND;       // [ND]
    float* gagg = vMg + ND;       // [ND] gelu(agg)
    int* ibase  = (int*)(gagg + ND);
    int* deg    = ibase;                    // [N]
    int* rowptr = deg + Nn;                 // [N+1]
    int* cursor = rowptr + Nn + 1;          // [N]
    unsigned int* col = (unsigned int*)(cursor + Nn);  // [2E]
    float* h1 = kAf;      // overlay [N,512]
    float* x1 = out;      // x1 staged in d_out

    const int ln_grid = (Nn + 3) / 4;
    const int mg = (Nn + 127) / 128;

    // 1. xn = LN1(x)
    ln_kernel<<<ln_grid, 256, 0, stream>>>(x, ln1_g, ln1_b, xn, Nn);
    // 2. kqv = xn @ kqv_w + kqv_b
    gemm128<0><<<dim3(mg, 3), 256, 0, stream>>>(xn, kqv_w, kqv_b, kqvb,
                                                Nn, 384, 128, nullptr, nullptr, nullptr);
    // 3. per-node relation transforms
    rel_transform<<<(Nn + 1) / 2, 256, 0, stream>>>(
        kqvb, a_f, m_f, a_g, m_g, kAf, kAg, vMf, vMg, Nn);
    // 4. CSR build
    zero_deg<<<(Nn + 255) / 256, 256, 0, stream>>>(deg, Nn);
    count_deg<<<(E1 + 255) / 256, 256, 0, stream>>>(ef, E1, deg);
    count_deg<<<(E2 + 255) / 256, 256, 0, stream>>>(eg, E2, deg);
    scan_kernel<<<1, 1024, 0, stream>>>(deg, rowptr, cursor, Nn);
    fill_csr<<<(E1 + 255) / 256, 256, 0, stream>>>(ef, E1, 0u, cursor, col);
    fill_csr<<<(E2 + 255) / 256, 256, 0, stream>>>(eg, E2, 1u, cursor, col);
    // 5. fused: logits + online segment softmax + weighted agg + gelu
    fused_agg<<<(Nn * 8) / 16, 256, 0, stream>>>(
        rowptr, col, kqvb, kAf, kAg, vMf, vMg, p_f, p_g, gagg, Nn);
    // 6. x1 = x + sig*(gagg @ out_w + out_b) + (1-sig)*xn   (into d_out)
    gemm128<2><<<dim3(mg, 1), 256, 0, stream>>>(gagg, out_w, out_b, x1,
                                                Nn, 128, 128, x, xn, skip);
    // 7. xn2 = LN2(x1)
    ln_kernel<<<ln_grid, 256, 0, stream>>>(x1, ln2_g, ln2_b, xn, Nn);
    // 8. h1 = gelu(xn2 @ w1 + b1)
    gemm128<1><<<dim3(mg, 4), 256, 0, stream>>>(xn, w1, b1, h1,
                                                Nn, 512, 128, nullptr, nullptr, nullptr);
    // 9. out = x1 + h1 @ w2 + b2
    gemm128<3><<<dim3(mg, 1), 256, 0, stream>>>(h1, w2, b2, out,
                                                Nn, 128, 512, x1, nullptr, nullptr);
}

// Round 9
// 871.775 us; speedup vs baseline: 1.0139x; 1.0139x over previous
//
#include <hip/hip_runtime.h>
#include <math.h>

// ---------------------------------------------------------------------------
// HGT transformer layer. N=50000, D=128, H=8, DH=16, E=300000 per edge type.
// R5: CSR + fused online-softmax aggregation (5000 -> 872 us).
// R7: 128x128 double-buffered fp32 GEMM (total unchanged -> suspect VGPR cap).
// R9: fused_agg thinned (packed float2 kv, p folded, no-max softmax, __expf);
//     gemm128 gets __launch_bounds__(256,2) to lift possible VGPR cap.
// ---------------------------------------------------------------------------

__device__ __forceinline__ float gelu_exact(float x) {
    return 0.5f * x * (1.0f + erff(x * 0.70710678118654752f));
}

// --------------------------- LayerNorm (rows of 128) -----------------------
__global__ __launch_bounds__(256) void ln_kernel(
    const float* __restrict__ x, const float* __restrict__ g,
    const float* __restrict__ b, float* __restrict__ out, int nrows)
{
    int row  = (int)((blockIdx.x * 256 + threadIdx.x) >> 6);
    int lane = threadIdx.x & 63;
    if (row >= nrows) return;
    float2 xv = *(const float2*)&x[(size_t)row * 128 + lane * 2];
    float s = xv.x + xv.y;
#pragma unroll
    for (int off = 32; off >= 1; off >>= 1) s += __shfl_xor(s, off, 64);
    float mu = s * (1.0f / 128.0f);
    float d0 = xv.x - mu, d1 = xv.y - mu;
    float v = d0 * d0 + d1 * d1;
#pragma unroll
    for (int off = 32; off >= 1; off >>= 1) v += __shfl_xor(v, off, 64);
    float rs = rsqrtf(v * (1.0f / 128.0f) + 1e-5f);
    float2 gv = *(const float2*)&g[lane * 2];
    float2 bv = *(const float2*)&b[lane * 2];
    float2 o;
    o.x = d0 * rs * gv.x + bv.x;
    o.y = d1 * rs * gv.y + bv.y;
    *(float2*)&out[(size_t)row * 128 + lane * 2] = o;
}

// ------------------ fp32 GEMM, 128x128 tile, double-buffered ---------------
// C[M,N] = A[M,K] @ B[K,N] (+bias), epilogues:
//   0: +bias   1: gelu(+bias)   2: aux1 + s*(acc+bias) + (1-s)*aux2   3: aux1+acc+bias
// 256 threads; per-thread 8x8 = (2x4 rows) x (2x4 cols); BK=16.
// __launch_bounds__(256,2): cap 256 VGPR (acc=64 + frags + staging must NOT
// spill; bare (256) may let the compiler cap at 128 and spill to scratch).
// Requires: N % 128 == 0, K % 16 == 0.
template <int EPI>
__global__ __launch_bounds__(256, 2) void gemm128(
    const float* __restrict__ A, const float* __restrict__ B,
    const float* __restrict__ bias, float* __restrict__ C,
    int M, int N, int K,
    const float* __restrict__ aux1, const float* __restrict__ aux2,
    const float* __restrict__ skipp)
{
    const int LDT = 132;
    __shared__ __align__(16) float As[2][16 * 132];
    __shared__ __align__(16) float Bs[2][16 * 132];
    const int t  = threadIdx.x;
    const int bm = blockIdx.x * 128;
    const int bn = blockIdx.y * 128;
    const int tx = t & 15, ty = t >> 4;

    // staging coords
    const int ar0 = t >> 2;            // A rows: ar0, ar0+64
    const int akc = (t & 3) << 2;      // A k-chunk 0/4/8/12
    const int br  = t >> 5;            // B k-rows: br, br+8
    const int bnc = (t & 31) << 2;     // B col-chunk

    float acc[2][2][4][4] = {};
    float4 ra0, ra1, rb0, rb1;
    const float4 zero4 = make_float4(0.f, 0.f, 0.f, 0.f);

    // prologue: load tile k0=0 into regs
    {
        int g0 = bm + ar0, g1 = g0 + 64;
        ra0 = (g0 < M) ? *(const float4*)&A[(size_t)g0 * K + akc] : zero4;
        ra1 = (g1 < M) ? *(const float4*)&A[(size_t)g1 * K + akc] : zero4;
        rb0 = *(const float4*)&B[(size_t)br * N + bn + bnc];
        rb1 = *(const float4*)&B[(size_t)(br + 8) * N + bn + bnc];
    }

    int buf = 0;
    for (int k0 = 0; k0 < K; k0 += 16) {
        // stage regs -> LDS[buf]
        {
            float* Ab = &As[buf][0];
            Ab[(akc + 0) * LDT + ar0] = ra0.x;
            Ab[(akc + 1) * LDT + ar0] = ra0.y;
            Ab[(akc + 2) * LDT + ar0] = ra0.z;
            Ab[(akc + 3) * LDT + ar0] = ra0.w;
            Ab[(akc + 0) * LDT + ar0 + 64] = ra1.x;
            Ab[(akc + 1) * LDT + ar0 + 64] = ra1.y;
            Ab[(akc + 2) * LDT + ar0 + 64] = ra1.z;
            Ab[(akc + 3) * LDT + ar0 + 64] = ra1.w;
            float* Bb = &Bs[buf][0];
            *(float4*)&Bb[br * LDT + bnc] = rb0;
            *(float4*)&Bb[(br + 8) * LDT + bnc] = rb1;
        }
        __syncthreads();

        // prefetch next tile into regs (overlaps with compute below)
        if (k0 + 16 < K) {
            int g0 = bm + ar0, g1 = g0 + 64;
            int kn = k0 + 16;
            ra0 = (g0 < M) ? *(const float4*)&A[(size_t)g0 * K + kn + akc] : zero4;
            ra1 = (g1 < M) ? *(const float4*)&A[(size_t)g1 * K + kn + akc] : zero4;
            rb0 = *(const float4*)&B[(size_t)(kn + br) * N + bn + bnc];
            rb1 = *(const float4*)&B[(size_t)(kn + br + 8) * N + bn + bnc];
        }

        const float* Ab = &As[buf][0];
        const float* Bb = &Bs[buf][0];
#pragma unroll
        for (int kk = 0; kk < 16; ++kk) {
            float4 a0 = *(const float4*)&Ab[kk * LDT + (ty << 2)];
            float4 a1 = *(const float4*)&Ab[kk * LDT + 64 + (ty << 2)];
            float4 b0 = *(const float4*)&Bb[kk * LDT + (tx << 2)];
            float4 b1 = *(const float4*)&Bb[kk * LDT + 64 + (tx << 2)];
            const float av[8] = {a0.x, a0.y, a0.z, a0.w, a1.x, a1.y, a1.z, a1.w};
            const float bv[8] = {b0.x, b0.y, b0.z, b0.w, b1.x, b1.y, b1.z, b1.w};
#pragma unroll
            for (int mi = 0; mi < 2; ++mi)
#pragma unroll
                for (int i = 0; i < 4; ++i)
#pragma unroll
                    for (int ni = 0; ni < 2; ++ni)
#pragma unroll
                        for (int j = 0; j < 4; ++j)
                            acc[mi][ni][i][j] += av[mi * 4 + i] * bv[ni * 4 + j];
        }
        buf ^= 1;
    }

    float s = 0.0f;
    if (EPI == 2) s = 1.0f / (1.0f + expf(-skipp[0]));
    float bbv[2][4];
    {
        float4 b0 = *(const float4*)&bias[bn + (tx << 2)];
        float4 b1 = *(const float4*)&bias[bn + 64 + (tx << 2)];
        bbv[0][0] = b0.x; bbv[0][1] = b0.y; bbv[0][2] = b0.z; bbv[0][3] = b0.w;
        bbv[1][0] = b1.x; bbv[1][1] = b1.y; bbv[1][2] = b1.z; bbv[1][3] = b1.w;
    }

#pragma unroll
    for (int mi = 0; mi < 2; ++mi)
#pragma unroll
        for (int i = 0; i < 4; ++i) {
            int r = bm + mi * 64 + (ty << 2) + i;
            if (r >= M) continue;
#pragma unroll
            for (int ni = 0; ni < 2; ++ni) {
                size_t cidx = (size_t)r * N + bn + ni * 64 + (tx << 2);
                float o[4];
#pragma unroll
                for (int j = 0; j < 4; ++j) {
                    float v = acc[mi][ni][i][j] + bbv[ni][j];
                    if (EPI == 1) v = gelu_exact(v);
                    o[j] = v;
                }
                if (EPI == 2) {
                    float4 a1 = *(const float4*)&aux1[cidx];
                    float4 a2 = *(const float4*)&aux2[cidx];
                    o[0] = a1.x + s * o[0] + (1.f - s) * a2.x;
                    o[1] = a1.y + s * o[1] + (1.f - s) * a2.y;
                    o[2] = a1.z + s * o[2] + (1.f - s) * a2.z;
                    o[3] = a1.w + s * o[3] + (1.f - s) * a2.w;
                } else if (EPI == 3) {
                    float4 a1 = *(const float4*)&aux1[cidx];
                    o[0] += a1.x; o[1] += a1.y; o[2] += a1.z; o[3] += a1.w;
                }
                *(float4*)&C[cidx] = make_float4(o[0], o[1], o[2], o[3]);
            }
        }
}

// ------------------- per-node relation transforms --------------------------
// Packed output: kv2[type*N + n][foff] = (k_rel * p/sqrt(DH), v_rel).
__global__ __launch_bounds__(256) void rel_transform(
    const float* __restrict__ kqv,
    const float* __restrict__ a_f, const float* __restrict__ m_f,
    const float* __restrict__ a_g, const float* __restrict__ m_g,
    const float* __restrict__ p_f, const float* __restrict__ p_g,
    float2* __restrict__ kvF, float2* __restrict__ kvG, int nnodes)
{
    __shared__ float sAf[8 * 16 * 17], sMf[8 * 16 * 17];
    __shared__ float sAg[8 * 16 * 17], sMg[8 * 16 * 17];
    for (int i = threadIdx.x; i < 2048; i += 256) {
        int o = (i >> 4) * 17 + (i & 15);
        sAf[o] = a_f[i]; sMf[o] = m_f[i];
        sAg[o] = a_g[i]; sMg[o] = m_g[i];
    }
    __syncthreads();
    int t = threadIdx.x;
    int f = t & 15, h = (t >> 4) & 7, nl = t >> 7;
    int n = blockIdx.x * 2 + nl;
    if (n >= nnodes) return;
    const float* kp = &kqv[(size_t)n * 384 + h * 16];
    const float* vp = kp + 256;
    float kd[16], vd[16];
#pragma unroll
    for (int i4 = 0; i4 < 4; ++i4) {
        float4 k4 = *(const float4*)&kp[i4 * 4];
        float4 v4 = *(const float4*)&vp[i4 * 4];
        kd[i4 * 4 + 0] = k4.x; kd[i4 * 4 + 1] = k4.y;
        kd[i4 * 4 + 2] = k4.z; kd[i4 * 4 + 3] = k4.w;
        vd[i4 * 4 + 0] = v4.x; vd[i4 * 4 + 1] = v4.y;
        vd[i4 * 4 + 2] = v4.z; vd[i4 * 4 + 3] = v4.w;
    }
    float rkf = 0.f, rkg = 0.f, rvf = 0.f, rvg = 0.f;
#pragma unroll
    for (int d = 0; d < 16; ++d) {
        int idx = (h * 16 + d) * 17 + f;
        rkf += kd[d] * sAf[idx];
        rkg += kd[d] * sAg[idx];
        rvf += vd[d] * sMf[idx];
        rvg += vd[d] * sMg[idx];
    }
    float cf = p_f[h] * 0.25f;   // p / sqrt(DH) folded into k_rel
    float cg = p_g[h] * 0.25f;
    size_t o = (size_t)n * 128 + h * 16 + f;
    kvF[o] = make_float2(rkf * cf, rvf);
    kvG[o] = make_float2(rkg * cg, rvg);
}

// -------------------- CSR build ---------------------------------------------
__global__ __launch_bounds__(256) void zero_deg(int* __restrict__ deg, int n) {
    int i = blockIdx.x * 256 + threadIdx.x;
    if (i < n) deg[i] = 0;
}

__global__ __launch_bounds__(256) void count_deg(
    const int* __restrict__ edge, int E, int* __restrict__ deg)
{
    int e = blockIdx.x * 256 + threadIdx.x;
    if (e >= E) return;
    atomicAdd(&deg[edge[E + e]], 1);
}

// single-block 2-level exclusive scan: deg[n] -> rowptr[n+1], cursor[n]
__global__ __launch_bounds__(1024) void scan_kernel(
    const int* __restrict__ deg, int* __restrict__ rowptr,
    int* __restrict__ cursor, int n)
{
    const int tid = threadIdx.x;
    const int CH = (n + 1023) / 1024;
    int beg = tid * CH, end = min(beg + CH, n);
    int s = 0;
    for (int i = beg; i < end; ++i) s += deg[i];
    __shared__ int tmp[1024];
    tmp[tid] = s;
    __syncthreads();
    for (int off = 1; off < 1024; off <<= 1) {
        int t = (tid >= off) ? tmp[tid - off] : 0;
        __syncthreads();
        tmp[tid] += t;
        __syncthreads();
    }
    int run = tmp[tid] - s;  // exclusive prefix of this chunk
    for (int i = beg; i < end; ++i) {
        int d = deg[i];
        rowptr[i] = run;
        cursor[i] = run;
        run += d;
    }
    if (tid == 1023) rowptr[n] = run;
}

// col entry = src + addbase (addbase = 0 for type f, N for type g), so the
// aggregation indexes one packed [2N][128] float2 array with no type select.
__global__ __launch_bounds__(256) void fill_csr(
    const int* __restrict__ edge, int E, int addbase,
    int* __restrict__ cursor, unsigned int* __restrict__ col)
{
    int e = blockIdx.x * 256 + threadIdx.x;
    if (e >= E) return;
    int src = edge[e], dst = edge[E + e];
    int pos = atomicAdd(&cursor[dst], 1);
    col[pos] = (unsigned int)(src + addbase);
}

// -------------------- fused gather + softmax + gelu ------------------------
// 16 lanes per (dst, head); a wave's 4 tasks share one dst -> uniform loop,
// coalesced 512B gathers. No max subtraction: logits are O(1) for this
// model scale (softmax shift-invariant; exp safely in fp32 range).
__global__ __launch_bounds__(256) void fused_agg(
    const int* __restrict__ rowptr, const unsigned int* __restrict__ col,
    const float* __restrict__ kqv, const float2* __restrict__ kv2,
    float* __restrict__ outg, int nnodes)
{
    int task = blockIdx.x * 16 + (threadIdx.x >> 4);
    int f    = threadIdx.x & 15;
    if (task >= nnodes * 8) return;
    int dst = task >> 3, h = task & 7;
    const int foff = h * 16 + f;
    float q = kqv[(size_t)dst * 384 + 128 + foff];
    int i = rowptr[dst], end = rowptr[dst + 1];
    float s = 0.f, o = 0.f;
    for (; i < end; ++i) {
        unsigned int cv = col[i];
        float2 kv = kv2[(size_t)cv * 128 + foff];
        float part = q * kv.x;
        part += __shfl_xor(part, 1, 16);
        part += __shfl_xor(part, 2, 16);
        part += __shfl_xor(part, 4, 16);
        part += __shfl_xor(part, 8, 16);
        float ev = __expf(part);
        s += ev;
        o = fmaf(ev, kv.y, o);
    }
    float r = o / (s + 1e-16f);   // deg==0 -> 0, matches reference
    outg[(size_t)dst * 128 + foff] = gelu_exact(r);
}

// ---------------------------------------------------------------------------
extern "C" void kernel_launch(void* const* d_in, const int* in_sizes, int n_in,
                              void* d_out, int out_size, void* d_ws, size_t ws_size,
                              hipStream_t stream)
{
    const float* x     = (const float*)d_in[0];
    const int*   ef    = (const int*)d_in[1];
    const int*   eg    = (const int*)d_in[2];
    const float* kqv_w = (const float*)d_in[3];
    const float* kqv_b = (const float*)d_in[4];
    const float* a_f   = (const float*)d_in[5];
    const float* m_f   = (const float*)d_in[6];
    const float* p_f   = (const float*)d_in[7];
    const float* a_g   = (const float*)d_in[8];
    const float* m_g   = (const float*)d_in[9];
    const float* p_g   = (const float*)d_in[10];
    const float* out_w = (const float*)d_in[11];
    const float* out_b = (const float*)d_in[12];
    const float* skip  = (const float*)d_in[13];
    const float* ln1_g = (const float*)d_in[14];
    const float* ln1_b = (const float*)d_in[15];
    const float* ln2_g = (const float*)d_in[16];
    const float* ln2_b = (const float*)d_in[17];
    const float* w1    = (const float*)d_in[18];
    const float* b1    = (const float*)d_in[19];
    const float* w2    = (const float*)d_in[20];
    const float* b2    = (const float*)d_in[21];
    float* out = (float*)d_out;

    const int D  = 128;
    const int Nn = in_sizes[0] / D;   // 50000
    const int E1 = in_sizes[1] / 2;   // 300000
    const int E2 = in_sizes[2] / 2;   // 300000

    // ---- workspace: 9*ND floats + (3N+1+2E) ints. Overlays as before:
    // kvF/kvG (4*ND floats total) at old kAf..vMg span; h1 overlays them.
    float* ws = (float*)d_ws;
    size_t ND = (size_t)Nn * D;
    float* xn   = ws;             // [ND]
    float* kqvb = xn + ND;        // [3*ND] k|q|v
    float2* kvF = (float2*)(kqvb + 3 * ND);  // [ND] float2 = 2*ND floats
    float2* kvG = kvF + ND;                  // [ND] float2
    float* gagg = kqvb + 3 * ND + 4 * ND;    // [ND] gelu(agg)
    int* ibase  = (int*)(gagg + ND);
    int* deg    = ibase;                    // [N]
    int* rowptr = deg + Nn;                 // [N+1]
    int* cursor = rowptr + Nn + 1;          // [N]
    unsigned int* col = (unsigned int*)(cursor + Nn);  // [2E]
    float* h1 = (float*)kvF;  // overlay [N,512]
    float* x1 = out;          // x1 staged in d_out

    const int ln_grid = (Nn + 3) / 4;
    const int mg = (Nn + 127) / 128;

    // 1. xn = LN1(x)
    ln_kernel<<<ln_grid, 256, 0, stream>>>(x, ln1_g, ln1_b, xn, Nn);
    // 2. kqv = xn @ kqv_w + kqv_b
    gemm128<0><<<dim3(mg, 3), 256, 0, stream>>>(xn, kqv_w, kqv_b, kqvb,
                                                Nn, 384, 128, nullptr, nullptr, nullptr);
    // 3. per-node relation transforms (packed, p folded)
    rel_transform<<<(Nn + 1) / 2, 256, 0, stream>>>(
        kqvb, a_f, m_f, a_g, m_g, p_f, p_g, kvF, kvG, Nn);
    // 4. CSR build
    zero_deg<<<(Nn + 255) / 256, 256, 0, stream>>>(deg, Nn);
    count_deg<<<(E1 + 255) / 256, 256, 0, stream>>>(ef, E1, deg);
    count_deg<<<(E2 + 255) / 256, 256, 0, stream>>>(eg, E2, deg);
    scan_kernel<<<1, 1024, 0, stream>>>(deg, rowptr, cursor, Nn);
    fill_csr<<<(E1 + 255) / 256, 256, 0, stream>>>(ef, E1, 0, cursor, col);
    fill_csr<<<(E2 + 255) / 256, 256, 0, stream>>>(eg, E2, Nn, cursor, col);
    // 5. fused: logits + segment softmax + weighted agg + gelu
    fused_agg<<<(Nn * 8) / 16, 256, 0, stream>>>(
        rowptr, col, kqvb, kvF, gagg, Nn);
    // 6. x1 = x + sig*(gagg @ out_w + out_b) + (1-sig)*xn   (into d_out)
    gemm128<2><<<dim3(mg, 1), 256, 0, stream>>>(gagg, out_w, out_b, x1,
                                                Nn, 128, 128, x, xn, skip);
    // 7. xn2 = LN2(x1)
    ln_kernel<<<ln_grid, 256, 0, stream>>>(x1, ln2_g, ln2_b, xn, Nn);
    // 8. h1 = gelu(xn2 @ w1 + b1)
    gemm128<1><<<dim3(mg, 4), 256, 0, stream>>>(xn, w1, b1, h1,
                                                Nn, 512, 128, nullptr, nullptr, nullptr);
    // 9. out = x1 + h1 @ w2 + b2
    gemm128<3><<<dim3(mg, 1), 256, 0, stream>>>(h1, w2, b2, out,
                                                Nn, 128, 512, x1, nullptr, nullptr);
}

// Round 11
// 744.488 us; speedup vs baseline: 1.1873x; 1.1710x over previous
//
#include <hip/hip_runtime.h>
#include <math.h>

// ---------------------------------------------------------------------------
// HGT transformer layer. N=50000, D=128, H=8, DH=16, E=300000 per edge type.
// R5:  CSR + fused online-softmax aggregation (5000 -> 872 us).
// R9:  thinned fused_agg (packed float2, folded p, __expf).
// R10: GEMMs -> bf16x3 MFMA (hi/lo split, fp32-accurate). fp32 vector GEMM
//      was issue/latency-bound at 40 TF (VALUBusy 44%, Occ 19%); bf16x3 is
//      HBM-bound instead.
// ---------------------------------------------------------------------------

using bf16x8 = __attribute__((ext_vector_type(8))) short;
using f32x4  = __attribute__((ext_vector_type(4))) float;

__device__ __forceinline__ float gelu_exact(float x) {
    return 0.5f * x * (1.0f + erff(x * 0.70710678118654752f));
}

__device__ __forceinline__ unsigned short f2bf(float x) {  // RNE float->bf16
    unsigned int u = __float_as_uint(x);
    u += 0x7fffu + ((u >> 16) & 1u);
    return (unsigned short)(u >> 16);
}
__device__ __forceinline__ float bf2f(unsigned short h) {
    return __uint_as_float(((unsigned int)h) << 16);
}

// --------------------------- LayerNorm (rows of 128) -----------------------
__global__ __launch_bounds__(256) void ln_kernel(
    const float* __restrict__ x, const float* __restrict__ g,
    const float* __restrict__ b, float* __restrict__ out, int nrows)
{
    int row  = (int)((blockIdx.x * 256 + threadIdx.x) >> 6);
    int lane = threadIdx.x & 63;
    if (row >= nrows) return;
    float2 xv = *(const float2*)&x[(size_t)row * 128 + lane * 2];
    float s = xv.x + xv.y;
#pragma unroll
    for (int off = 32; off >= 1; off >>= 1) s += __shfl_xor(s, off, 64);
    float mu = s * (1.0f / 128.0f);
    float d0 = xv.x - mu, d1 = xv.y - mu;
    float v = d0 * d0 + d1 * d1;
#pragma unroll
    for (int off = 32; off >= 1; off >>= 1) v += __shfl_xor(v, off, 64);
    float rs = rsqrtf(v * (1.0f / 128.0f) + 1e-5f);
    float2 gv = *(const float2*)&g[lane * 2];
    float2 bv = *(const float2*)&b[lane * 2];
    float2 o;
    o.x = d0 * rs * gv.x + bv.x;
    o.y = d1 * rs * gv.y + bv.y;
    *(float2*)&out[(size_t)row * 128 + lane * 2] = o;
}

// ---------------- bf16x3 MFMA GEMM, 128x128 tile ---------------------------
// C[M,N] = A[M,K] @ B[K,N] (+bias); A,B fp32 in global, split to bf16 hi/lo
// during LDS staging. acc += Ah*Bh + Ah*Bl + Al*Bh (fp32 MFMA accumulate).
// 256 thr = 4 waves (2x2 of 64x64); per wave 4x4 frags of 16x16x32; BK=32.
// LDS row stride 40 bf16 (80B): 16B-aligned b128 frag reads, banks spread.
// Epilogues: 0:+bias 1:gelu 2:aux1+s*(acc+b)+(1-s)*aux2 3:aux1+acc+bias.
// Requires N%128==0, K%32==0.
template <int EPI>
__global__ __launch_bounds__(256) void gemm_bf3(
    const float* __restrict__ A, const float* __restrict__ B,
    const float* __restrict__ bias, float* __restrict__ C,
    int M, int N, int K,
    const float* __restrict__ aux1, const float* __restrict__ aux2,
    const float* __restrict__ skipp)
{
    __shared__ __align__(16) unsigned short sAh[128 * 40], sAl[128 * 40];
    __shared__ __align__(16) unsigned short sBh[128 * 40], sBl[128 * 40];
    const int t    = threadIdx.x;
    const int bm   = blockIdx.x * 128;
    const int bn   = blockIdx.y * 128;
    const int lane = t & 63;
    const int wave = t >> 6;
    const int wm   = (wave >> 1) * 64;   // wave row origin in tile
    const int wn   = (wave & 1) * 64;    // wave col origin in tile
    const int lrow = lane & 15;          // fragment row/col
    const int lkg  = lane >> 4;          // k-group (8 bf16 each)

    // staging coords: 2 threads per row/col, each 16 k's
    const int s_rc = t >> 1;             // A-row / B-col 0..127
    const int s_kc = (t & 1) * 16;       // k offset 0/16

    f32x4 acc[4][4] = {};

    for (int k0 = 0; k0 < K; k0 += 32) {
        // ---- stage A[128][32]: coalesced float4 reads, hi/lo to LDS
        {
            const float4* ap = (const float4*)&A[(size_t)(bm + s_rc) * K + k0 + s_kc];
            unsigned int* dh = (unsigned int*)sAh + s_rc * 20 + (s_kc >> 1);
            unsigned int* dl = (unsigned int*)sAl + s_rc * 20 + (s_kc >> 1);
#pragma unroll
            for (int j = 0; j < 4; ++j) {
                float4 v = ap[j];
                unsigned short h0 = f2bf(v.x), h1 = f2bf(v.y),
                               h2 = f2bf(v.z), h3 = f2bf(v.w);
                unsigned short l0 = f2bf(v.x - bf2f(h0)), l1 = f2bf(v.y - bf2f(h1)),
                               l2 = f2bf(v.z - bf2f(h2)), l3 = f2bf(v.w - bf2f(h3));
                dh[j * 2 + 0] = (unsigned int)h0 | ((unsigned int)h1 << 16);
                dh[j * 2 + 1] = (unsigned int)h2 | ((unsigned int)h3 << 16);
                dl[j * 2 + 0] = (unsigned int)l0 | ((unsigned int)l1 << 16);
                dl[j * 2 + 1] = (unsigned int)l2 | ((unsigned int)l3 << 16);
            }
        }
        // ---- stage B[32][128] transposed -> sB[col][k]
        {
            const float* bp = &B[(size_t)(k0 + s_kc) * N + bn + s_rc];
            unsigned int* dh = (unsigned int*)sBh + s_rc * 20 + (s_kc >> 1);
            unsigned int* dl = (unsigned int*)sBl + s_rc * 20 + (s_kc >> 1);
#pragma unroll
            for (int j = 0; j < 8; ++j) {
                float x0 = bp[(size_t)(2 * j) * N];
                float x1 = bp[(size_t)(2 * j + 1) * N];
                unsigned short h0 = f2bf(x0), l0 = f2bf(x0 - bf2f(h0));
                unsigned short h1 = f2bf(x1), l1 = f2bf(x1 - bf2f(h1));
                dh[j] = (unsigned int)h0 | ((unsigned int)h1 << 16);
                dl[j] = (unsigned int)l0 | ((unsigned int)l1 << 16);
            }
        }
        __syncthreads();

        // ---- fragments + MFMA (A: row=lrow, k=lkg*8+i ; B: col=lrow, same k)
        bf16x8 ah[4], al[4];
#pragma unroll
        for (int mi = 0; mi < 4; ++mi) {
            int r = wm + mi * 16 + lrow;
            ah[mi] = *(const bf16x8*)&sAh[r * 40 + lkg * 8];
            al[mi] = *(const bf16x8*)&sAl[r * 40 + lkg * 8];
        }
#pragma unroll
        for (int ni = 0; ni < 4; ++ni) {
            int c = wn + ni * 16 + lrow;
            bf16x8 bh = *(const bf16x8*)&sBh[c * 40 + lkg * 8];
            bf16x8 bl = *(const bf16x8*)&sBl[c * 40 + lkg * 8];
#pragma unroll
            for (int mi = 0; mi < 4; ++mi) {
                acc[mi][ni] = __builtin_amdgcn_mfma_f32_16x16x32_bf16(ah[mi], bh, acc[mi][ni], 0, 0, 0);
                acc[mi][ni] = __builtin_amdgcn_mfma_f32_16x16x32_bf16(ah[mi], bl, acc[mi][ni], 0, 0, 0);
                acc[mi][ni] = __builtin_amdgcn_mfma_f32_16x16x32_bf16(al[mi], bh, acc[mi][ni], 0, 0, 0);
            }
        }
        __syncthreads();
    }

    // ---- epilogue. C/D layout (verified): col = lane&15, row = (lane>>4)*4+reg
    float sgk = 0.0f;
    if (EPI == 2) sgk = 1.0f / (1.0f + expf(-skipp[0]));
#pragma unroll
    for (int mi = 0; mi < 4; ++mi) {
#pragma unroll
        for (int r4 = 0; r4 < 4; ++r4) {
            int row = bm + wm + mi * 16 + lkg * 4 + r4;
            if (row >= M) continue;
#pragma unroll
            for (int ni = 0; ni < 4; ++ni) {
                int col = bn + wn + ni * 16 + lrow;
                size_t cidx = (size_t)row * N + col;
                float v = acc[mi][ni][r4] + bias[col];
                if (EPI == 1) v = gelu_exact(v);
                if (EPI == 2) v = aux1[cidx] + sgk * v + (1.0f - sgk) * aux2[cidx];
                if (EPI == 3) v = aux1[cidx] + v;
                C[cidx] = v;
            }
        }
    }
}

// ------------------- per-node relation transforms --------------------------
// Packed output: kv[n][foff] = (k_rel * p/sqrt(DH), v_rel), per edge type.
__global__ __launch_bounds__(256) void rel_transform(
    const float* __restrict__ kqv,
    const float* __restrict__ a_f, const float* __restrict__ m_f,
    const float* __restrict__ a_g, const float* __restrict__ m_g,
    const float* __restrict__ p_f, const float* __restrict__ p_g,
    float2* __restrict__ kvF, float2* __restrict__ kvG, int nnodes)
{
    __shared__ float sAf[8 * 16 * 17], sMf[8 * 16 * 17];
    __shared__ float sAg[8 * 16 * 17], sMg[8 * 16 * 17];
    for (int i = threadIdx.x; i < 2048; i += 256) {
        int o = (i >> 4) * 17 + (i & 15);
        sAf[o] = a_f[i]; sMf[o] = m_f[i];
        sAg[o] = a_g[i]; sMg[o] = m_g[i];
    }
    __syncthreads();
    int t = threadIdx.x;
    int f = t & 15, h = (t >> 4) & 7, nl = t >> 7;
    int n = blockIdx.x * 2 + nl;
    if (n >= nnodes) return;
    const float* kp = &kqv[(size_t)n * 384 + h * 16];
    const float* vp = kp + 256;
    float kd[16], vd[16];
#pragma unroll
    for (int i4 = 0; i4 < 4; ++i4) {
        float4 k4 = *(const float4*)&kp[i4 * 4];
        float4 v4 = *(const float4*)&vp[i4 * 4];
        kd[i4 * 4 + 0] = k4.x; kd[i4 * 4 + 1] = k4.y;
        kd[i4 * 4 + 2] = k4.z; kd[i4 * 4 + 3] = k4.w;
        vd[i4 * 4 + 0] = v4.x; vd[i4 * 4 + 1] = v4.y;
        vd[i4 * 4 + 2] = v4.z; vd[i4 * 4 + 3] = v4.w;
    }
    float rkf = 0.f, rkg = 0.f, rvf = 0.f, rvg = 0.f;
#pragma unroll
    for (int d = 0; d < 16; ++d) {
        int idx = (h * 16 + d) * 17 + f;
        rkf += kd[d] * sAf[idx];
        rkg += kd[d] * sAg[idx];
        rvf += vd[d] * sMf[idx];
        rvg += vd[d] * sMg[idx];
    }
    float cf = p_f[h] * 0.25f;   // p / sqrt(DH) folded into k_rel
    float cg = p_g[h] * 0.25f;
    size_t o = (size_t)n * 128 + h * 16 + f;
    kvF[o] = make_float2(rkf * cf, rvf);
    kvG[o] = make_float2(rkg * cg, rvg);
}

// -------------------- CSR build ---------------------------------------------
__global__ __launch_bounds__(256) void zero_deg(int* __restrict__ deg, int n) {
    int i = blockIdx.x * 256 + threadIdx.x;
    if (i < n) deg[i] = 0;
}

__global__ __launch_bounds__(256) void count_deg(
    const int* __restrict__ edge, int E, int* __restrict__ deg)
{
    int e = blockIdx.x * 256 + threadIdx.x;
    if (e >= E) return;
    atomicAdd(&deg[edge[E + e]], 1);
}

// single-block 2-level exclusive scan: deg[n] -> rowptr[n+1], cursor[n]
__global__ __launch_bounds__(1024) void scan_kernel(
    const int* __restrict__ deg, int* __restrict__ rowptr,
    int* __restrict__ cursor, int n)
{
    const int tid = threadIdx.x;
    const int CH = (n + 1023) / 1024;
    int beg = tid * CH, end = min(beg + CH, n);
    int s = 0;
    for (int i = beg; i < end; ++i) s += deg[i];
    __shared__ int tmp[1024];
    tmp[tid] = s;
    __syncthreads();
    for (int off = 1; off < 1024; off <<= 1) {
        int t = (tid >= off) ? tmp[tid - off] : 0;
        __syncthreads();
        tmp[tid] += t;
        __syncthreads();
    }
    int run = tmp[tid] - s;  // exclusive prefix of this chunk
    for (int i = beg; i < end; ++i) {
        int d = deg[i];
        rowptr[i] = run;
        cursor[i] = run;
        run += d;
    }
    if (tid == 1023) rowptr[n] = run;
}

// col entry = src + addbase (0 for type f, N for type g): aggregation indexes
// one packed [2N][128] float2 array with no type select.
__global__ __launch_bounds__(256) void fill_csr(
    const int* __restrict__ edge, int E, int addbase,
    int* __restrict__ cursor, unsigned int* __restrict__ col)
{
    int e = blockIdx.x * 256 + threadIdx.x;
    if (e >= E) return;
    int src = edge[e], dst = edge[E + e];
    int pos = atomicAdd(&cursor[dst], 1);
    col[pos] = (unsigned int)(src + addbase);
}

// -------------------- fused gather + softmax + gelu ------------------------
__global__ __launch_bounds__(256) void fused_agg(
    const int* __restrict__ rowptr, const unsigned int* __restrict__ col,
    const float* __restrict__ kqv, const float2* __restrict__ kv2,
    float* __restrict__ outg, int nnodes)
{
    int task = blockIdx.x * 16 + (threadIdx.x >> 4);
    int f    = threadIdx.x & 15;
    if (task >= nnodes * 8) return;
    int dst = task >> 3, h = task & 7;
    const int foff = h * 16 + f;
    float q = kqv[(size_t)dst * 384 + 128 + foff];
    int i = rowptr[dst], end = rowptr[dst + 1];
    float s = 0.f, o = 0.f;
    for (; i < end; ++i) {
        unsigned int cv = col[i];
        float2 kv = kv2[(size_t)cv * 128 + foff];
        float part = q * kv.x;
        part += __shfl_xor(part, 1, 16);
        part += __shfl_xor(part, 2, 16);
        part += __shfl_xor(part, 4, 16);
        part += __shfl_xor(part, 8, 16);
        float ev = __expf(part);
        s += ev;
        o = fmaf(ev, kv.y, o);
    }
    float r = o / (s + 1e-16f);   // deg==0 -> 0, matches reference
    outg[(size_t)dst * 128 + foff] = gelu_exact(r);
}

// ---------------------------------------------------------------------------
extern "C" void kernel_launch(void* const* d_in, const int* in_sizes, int n_in,
                              void* d_out, int out_size, void* d_ws, size_t ws_size,
                              hipStream_t stream)
{
    const float* x     = (const float*)d_in[0];
    const int*   ef    = (const int*)d_in[1];
    const int*   eg    = (const int*)d_in[2];
    const float* kqv_w = (const float*)d_in[3];
    const float* kqv_b = (const float*)d_in[4];
    const float* a_f   = (const float*)d_in[5];
    const float* m_f   = (const float*)d_in[6];
    const float* p_f   = (const float*)d_in[7];
    const float* a_g   = (const float*)d_in[8];
    const float* m_g   = (const float*)d_in[9];
    const float* p_g   = (const float*)d_in[10];
    const float* out_w = (const float*)d_in[11];
    const float* out_b = (const float*)d_in[12];
    const float* skip  = (const float*)d_in[13];
    const float* ln1_g = (const float*)d_in[14];
    const float* ln1_b = (const float*)d_in[15];
    const float* ln2_g = (const float*)d_in[16];
    const float* ln2_b = (const float*)d_in[17];
    const float* w1    = (const float*)d_in[18];
    const float* b1    = (const float*)d_in[19];
    const float* w2    = (const float*)d_in[20];
    const float* b2    = (const float*)d_in[21];
    float* out = (float*)d_out;

    const int D  = 128;
    const int Nn = in_sizes[0] / D;   // 50000
    const int E1 = in_sizes[1] / 2;   // 300000
    const int E2 = in_sizes[2] / 2;   // 300000

    // ---- workspace: 8*ND floats + (3N+1+2E) ints. Overlays:
    // kvF/kvG (4*ND floats) after kqvb; h1 overlays them; x1 staged in d_out.
    float* ws = (float*)d_ws;
    size_t ND = (size_t)Nn * D;
    float* xn   = ws;             // [ND]
    float* kqvb = xn + ND;        // [3*ND] k|q|v
    float2* kvF = (float2*)(kqvb + 3 * ND);  // [ND] float2
    float2* kvG = kvF + ND;                  // [ND] float2
    float* gagg = kqvb + 3 * ND + 4 * ND;    // [ND] gelu(agg)
    int* ibase  = (int*)(gagg + ND);
    int* deg    = ibase;                    // [N]
    int* rowptr = deg + Nn;                 // [N+1]
    int* cursor = rowptr + Nn + 1;          // [N]
    unsigned int* col = (unsigned int*)(cursor + Nn);  // [2E]
    float* h1 = (float*)kvF;  // overlay [N,512]
    float* x1 = out;          // x1 staged in d_out

    const int ln_grid = (Nn + 3) / 4;
    const int mg = (Nn + 127) / 128;

    // 1. xn = LN1(x)
    ln_kernel<<<ln_grid, 256, 0, stream>>>(x, ln1_g, ln1_b, xn, Nn);
    // 2. kqv = xn @ kqv_w + kqv_b
    gemm_bf3<0><<<dim3(mg, 3), 256, 0, stream>>>(xn, kqv_w, kqv_b, kqvb,
                                                 Nn, 384, 128, nullptr, nullptr, nullptr);
    // 3. per-node relation transforms (packed, p folded)
    rel_transform<<<(Nn + 1) / 2, 256, 0, stream>>>(
        kqvb, a_f, m_f, a_g, m_g, p_f, p_g, kvF, kvG, Nn);
    // 4. CSR build
    zero_deg<<<(Nn + 255) / 256, 256, 0, stream>>>(deg, Nn);
    count_deg<<<(E1 + 255) / 256, 256, 0, stream>>>(ef, E1, deg);
    count_deg<<<(E2 + 255) / 256, 256, 0, stream>>>(eg, E2, deg);
    scan_kernel<<<1, 1024, 0, stream>>>(deg, rowptr, cursor, Nn);
    fill_csr<<<(E1 + 255) / 256, 256, 0, stream>>>(ef, E1, 0, cursor, col);
    fill_csr<<<(E2 + 255) / 256, 256, 0, stream>>>(eg, E2, Nn, cursor, col);
    // 5. fused: logits + segment softmax + weighted agg + gelu
    fused_agg<<<(Nn * 8) / 16, 256, 0, stream>>>(
        rowptr, col, kqvb, kvF, gagg, Nn);
    // 6. x1 = x + sig*(gagg @ out_w + out_b) + (1-sig)*xn   (into d_out)
    gemm_bf3<2><<<dim3(mg, 1), 256, 0, stream>>>(gagg, out_w, out_b, x1,
                                                 Nn, 128, 128, x, xn, skip);
    // 7. xn2 = LN2(x1)
    ln_kernel<<<ln_grid, 256, 0, stream>>>(x1, ln2_g, ln2_b, xn, Nn);
    // 8. h1 = gelu(xn2 @ w1 + b1)
    gemm_bf3<1><<<dim3(mg, 4), 256, 0, stream>>>(xn, w1, b1, h1,
                                                 Nn, 512, 128, nullptr, nullptr, nullptr);
    // 9. out = x1 + h1 @ w2 + b2
    gemm_bf3<3><<<dim3(mg, 1), 256, 0, stream>>>(h1, w2, b2, out,
                                                 Nn, 128, 512, x1, nullptr, nullptr);
}

// Round 12
// 677.559 us; speedup vs baseline: 1.3045x; 1.0988x over previous
//
#include <hip/hip_runtime.h>
#include <math.h>

// ---------------------------------------------------------------------------
// HGT transformer layer. N=50000, D=128, H=8, DH=16, E=300000 per edge type.
// R5:  CSR + fused online-softmax aggregation (5000 -> 872 us).
// R10: bf16x3 MFMA GEMMs (872 -> 744).
// R12: pre-split bf16 hi/lo ONCE (weights transposed+split in tiny kernels;
//      activations split in producer epilogues) -- R11 GEMMs re-converted B
//      per M-block (391x waste). fused_agg: 4-wide pipelined gathers
//      (was latency-bound: VALUBusy 26%, 2.2 TB/s).
// ---------------------------------------------------------------------------

using bf16x8 = __attribute__((ext_vector_type(8))) short;
using us8    = __attribute__((ext_vector_type(8))) unsigned short;
using f32x4  = __attribute__((ext_vector_type(4))) float;

__device__ __forceinline__ float gelu_exact(float x) {
    return 0.5f * x * (1.0f + erff(x * 0.70710678118654752f));
}
__device__ __forceinline__ unsigned short f2bf(float x) {  // RNE float->bf16
    unsigned int u = __float_as_uint(x);
    u += 0x7fffu + ((u >> 16) & 1u);
    return (unsigned short)(u >> 16);
}
__device__ __forceinline__ float bf2f(unsigned short h) {
    return __uint_as_float(((unsigned int)h) << 16);
}

// --------------------------- LayerNorm (rows of 128) -----------------------
// Writes optional f32 (outf) and bf16 hi/lo split (outh/outl).
__global__ __launch_bounds__(256) void ln_kernel(
    const float* __restrict__ x, const float* __restrict__ g,
    const float* __restrict__ b, float* __restrict__ outf,
    unsigned short* __restrict__ outh, unsigned short* __restrict__ outl,
    int nrows)
{
    int row  = (int)((blockIdx.x * 256 + threadIdx.x) >> 6);
    int lane = threadIdx.x & 63;
    if (row >= nrows) return;
    float2 xv = *(const float2*)&x[(size_t)row * 128 + lane * 2];
    float s = xv.x + xv.y;
#pragma unroll
    for (int off = 32; off >= 1; off >>= 1) s += __shfl_xor(s, off, 64);
    float mu = s * (1.0f / 128.0f);
    float d0 = xv.x - mu, d1 = xv.y - mu;
    float v = d0 * d0 + d1 * d1;
#pragma unroll
    for (int off = 32; off >= 1; off >>= 1) v += __shfl_xor(v, off, 64);
    float rs = rsqrtf(v * (1.0f / 128.0f) + 1e-5f);
    float2 gv = *(const float2*)&g[lane * 2];
    float2 bv = *(const float2*)&b[lane * 2];
    float o0 = d0 * rs * gv.x + bv.x;
    float o1 = d1 * rs * gv.y + bv.y;
    size_t idx = (size_t)row * 128 + lane * 2;
    if (outf) *(float2*)&outf[idx] = make_float2(o0, o1);
    unsigned short h0 = f2bf(o0), h1 = f2bf(o1);
    *(ushort2*)&outh[idx] = make_ushort2(h0, h1);
    *(ushort2*)&outl[idx] = make_ushort2(f2bf(o0 - bf2f(h0)), f2bf(o1 - bf2f(h1)));
}

// ------------- weight transpose + bf16 hi/lo split (once per call) ---------
// W[K][N] f32 -> Wh,Wl [N][K] bf16. Grid (K/32, N/32), 256 thr (32x8).
__global__ __launch_bounds__(256) void transpose_split_w(
    const float* __restrict__ W, unsigned short* __restrict__ Wh,
    unsigned short* __restrict__ Wl, int K, int N)
{
    __shared__ unsigned short th[32][33], tl[32][33];
    int kt = blockIdx.x * 32, nt = blockIdx.y * 32;
    int tx = threadIdx.x & 31, ty = threadIdx.x >> 5;
#pragma unroll
    for (int j = 0; j < 32; j += 8) {
        float v = W[(size_t)(kt + ty + j) * N + nt + tx];
        unsigned short h = f2bf(v);
        th[ty + j][tx] = h;
        tl[ty + j][tx] = f2bf(v - bf2f(h));
    }
    __syncthreads();
#pragma unroll
    for (int j = 0; j < 32; j += 8) {
        size_t o = (size_t)(nt + ty + j) * K + kt + tx;
        Wh[o] = th[tx][ty + j];
        Wl[o] = tl[tx][ty + j];
    }
}

// ---------------- bf16x3 MFMA GEMM, pre-split operands ---------------------
// C = A@B + bias. A: [M][K] bf16 hi/lo. B: [N][K] bf16 hi/lo (pre-transposed).
// acc += Ah*Bh + Ah*Bl + Al*Bh. 4 waves (2x2 of 64x64), 4x4 frags 16x16x32,
// BK=32. LDS stride 40 bf16. Staging = pure 16B copies (no conversion).
// EPI: 0:+bias 1:gelu 2:aux1+s*(acc+b)+(1-s)*aux2 3:aux1+acc+bias.
// OBF=1: write bf16 hi/lo (Ch,Cl) instead of f32 C.
template <int EPI, int OBF>
__global__ __launch_bounds__(256) void gemm_bfp(
    const unsigned short* __restrict__ Ah, const unsigned short* __restrict__ Al,
    const unsigned short* __restrict__ Bh, const unsigned short* __restrict__ Bl,
    const float* __restrict__ bias, float* __restrict__ C,
    unsigned short* __restrict__ Ch, unsigned short* __restrict__ Cl,
    int M, int N, int K,
    const float* __restrict__ aux1, const float* __restrict__ aux2,
    const float* __restrict__ skipp)
{
    __shared__ __align__(16) unsigned short sAh[128 * 40], sAl[128 * 40];
    __shared__ __align__(16) unsigned short sBh[128 * 40], sBl[128 * 40];
    const int t    = threadIdx.x;
    const int bm   = blockIdx.x * 128;
    const int bn   = blockIdx.y * 128;
    const int lane = t & 63;
    const int wave = t >> 6;
    const int wm   = (wave >> 1) * 64;
    const int wn   = (wave & 1) * 64;
    const int lrow = lane & 15;
    const int lkg  = lane >> 4;

    const int s_rc = t >> 1;           // A-row / B-col 0..127
    const int s_kc = (t & 1) * 16;     // k offset 0/16

    f32x4 acc[4][4] = {};

    for (int k0 = 0; k0 < K; k0 += 32) {
        // pure-copy staging, 16B per load
        {
            size_t ga = (size_t)(bm + s_rc) * K + k0 + s_kc;
            size_t gb = (size_t)(bn + s_rc) * K + k0 + s_kc;
            int ld = s_rc * 40 + s_kc;
            *(us8*)&sAh[ld]     = *(const us8*)&Ah[ga];
            *(us8*)&sAh[ld + 8] = *(const us8*)&Ah[ga + 8];
            *(us8*)&sAl[ld]     = *(const us8*)&Al[ga];
            *(us8*)&sAl[ld + 8] = *(const us8*)&Al[ga + 8];
            *(us8*)&sBh[ld]     = *(const us8*)&Bh[gb];
            *(us8*)&sBh[ld + 8] = *(const us8*)&Bh[gb + 8];
            *(us8*)&sBl[ld]     = *(const us8*)&Bl[gb];
            *(us8*)&sBl[ld + 8] = *(const us8*)&Bl[gb + 8];
        }
        __syncthreads();

        bf16x8 ah[4], al[4];
#pragma unroll
        for (int mi = 0; mi < 4; ++mi) {
            int r = wm + mi * 16 + lrow;
            ah[mi] = *(const bf16x8*)&sAh[r * 40 + lkg * 8];
            al[mi] = *(const bf16x8*)&sAl[r * 40 + lkg * 8];
        }
#pragma unroll
        for (int ni = 0; ni < 4; ++ni) {
            int c = wn + ni * 16 + lrow;
            bf16x8 bh = *(const bf16x8*)&sBh[c * 40 + lkg * 8];
            bf16x8 bl = *(const bf16x8*)&sBl[c * 40 + lkg * 8];
#pragma unroll
            for (int mi = 0; mi < 4; ++mi) {
                acc[mi][ni] = __builtin_amdgcn_mfma_f32_16x16x32_bf16(ah[mi], bh, acc[mi][ni], 0, 0, 0);
                acc[mi][ni] = __builtin_amdgcn_mfma_f32_16x16x32_bf16(ah[mi], bl, acc[mi][ni], 0, 0, 0);
                acc[mi][ni] = __builtin_amdgcn_mfma_f32_16x16x32_bf16(al[mi], bh, acc[mi][ni], 0, 0, 0);
            }
        }
        __syncthreads();
    }

    // epilogue. C/D layout: col = lane&15, row = (lane>>4)*4 + reg
    float sgk = 0.0f;
    if (EPI == 2) sgk = 1.0f / (1.0f + expf(-skipp[0]));
#pragma unroll
    for (int mi = 0; mi < 4; ++mi) {
#pragma unroll
        for (int r4 = 0; r4 < 4; ++r4) {
            int row = bm + wm + mi * 16 + lkg * 4 + r4;
            if (row >= M) continue;
#pragma unroll
            for (int ni = 0; ni < 4; ++ni) {
                int col = bn + wn + ni * 16 + lrow;
                size_t cidx = (size_t)row * N + col;
                float v = acc[mi][ni][r4] + bias[col];
                if (EPI == 1) v = gelu_exact(v);
                if (EPI == 2) v = aux1[cidx] + sgk * v + (1.0f - sgk) * aux2[cidx];
                if (EPI == 3) v = aux1[cidx] + v;
                if (OBF) {
                    unsigned short h = f2bf(v);
                    Ch[cidx] = h;
                    Cl[cidx] = f2bf(v - bf2f(h));
                } else {
                    C[cidx] = v;
                }
            }
        }
    }
}

// ------------------- per-node relation transforms --------------------------
// kv[n][foff] = (k_rel * p/sqrt(DH), v_rel) per edge type.
__global__ __launch_bounds__(256) void rel_transform(
    const float* __restrict__ kqv,
    const float* __restrict__ a_f, const float* __restrict__ m_f,
    const float* __restrict__ a_g, const float* __restrict__ m_g,
    const float* __restrict__ p_f, const float* __restrict__ p_g,
    float2* __restrict__ kvF, float2* __restrict__ kvG, int nnodes)
{
    __shared__ float sAf[8 * 16 * 17], sMf[8 * 16 * 17];
    __shared__ float sAg[8 * 16 * 17], sMg[8 * 16 * 17];
    for (int i = threadIdx.x; i < 2048; i += 256) {
        int o = (i >> 4) * 17 + (i & 15);
        sAf[o] = a_f[i]; sMf[o] = m_f[i];
        sAg[o] = a_g[i]; sMg[o] = m_g[i];
    }
    __syncthreads();
    int t = threadIdx.x;
    int f = t & 15, h = (t >> 4) & 7, nl = t >> 7;
    int n = blockIdx.x * 2 + nl;
    if (n >= nnodes) return;
    const float* kp = &kqv[(size_t)n * 384 + h * 16];
    const float* vp = kp + 256;
    float kd[16], vd[16];
#pragma unroll
    for (int i4 = 0; i4 < 4; ++i4) {
        float4 k4 = *(const float4*)&kp[i4 * 4];
        float4 v4 = *(const float4*)&vp[i4 * 4];
        kd[i4 * 4 + 0] = k4.x; kd[i4 * 4 + 1] = k4.y;
        kd[i4 * 4 + 2] = k4.z; kd[i4 * 4 + 3] = k4.w;
        vd[i4 * 4 + 0] = v4.x; vd[i4 * 4 + 1] = v4.y;
        vd[i4 * 4 + 2] = v4.z; vd[i4 * 4 + 3] = v4.w;
    }
    float rkf = 0.f, rkg = 0.f, rvf = 0.f, rvg = 0.f;
#pragma unroll
    for (int d = 0; d < 16; ++d) {
        int idx = (h * 16 + d) * 17 + f;
        rkf += kd[d] * sAf[idx];
        rkg += kd[d] * sAg[idx];
        rvf += vd[d] * sMf[idx];
        rvg += vd[d] * sMg[idx];
    }
    float cf = p_f[h] * 0.25f;
    float cg = p_g[h] * 0.25f;
    size_t o = (size_t)n * 128 + h * 16 + f;
    kvF[o] = make_float2(rkf * cf, rvf);
    kvG[o] = make_float2(rkg * cg, rvg);
}

// -------------------- CSR build ---------------------------------------------
__global__ __launch_bounds__(256) void zero_deg(int* __restrict__ deg, int n) {
    int i = blockIdx.x * 256 + threadIdx.x;
    if (i < n) deg[i] = 0;
}

__global__ __launch_bounds__(256) void count_deg(
    const int* __restrict__ edge, int E, int* __restrict__ deg)
{
    int e = blockIdx.x * 256 + threadIdx.x;
    if (e >= E) return;
    atomicAdd(&deg[edge[E + e]], 1);
}

__global__ __launch_bounds__(1024) void scan_kernel(
    const int* __restrict__ deg, int* __restrict__ rowptr,
    int* __restrict__ cursor, int n)
{
    const int tid = threadIdx.x;
    const int CH = (n + 1023) / 1024;
    int beg = tid * CH, end = min(beg + CH, n);
    int s = 0;
    for (int i = beg; i < end; ++i) s += deg[i];
    __shared__ int tmp[1024];
    tmp[tid] = s;
    __syncthreads();
    for (int off = 1; off < 1024; off <<= 1) {
        int t = (tid >= off) ? tmp[tid - off] : 0;
        __syncthreads();
        tmp[tid] += t;
        __syncthreads();
    }
    int run = tmp[tid] - s;
    for (int i = beg; i < end; ++i) {
        int d = deg[i];
        rowptr[i] = run;
        cursor[i] = run;
        run += d;
    }
    if (tid == 1023) rowptr[n] = run;
}

__global__ __launch_bounds__(256) void fill_csr(
    const int* __restrict__ edge, int E, int addbase,
    int* __restrict__ cursor, unsigned int* __restrict__ col)
{
    int e = blockIdx.x * 256 + threadIdx.x;
    if (e >= E) return;
    int src = edge[e], dst = edge[E + e];
    int pos = atomicAdd(&cursor[dst], 1);
    col[pos] = (unsigned int)(src + addbase);
}

// -------------- fused gather + softmax + gelu (4-wide pipelined) -----------
// 16 lanes per (dst,head); wave's 4 tasks share dst. 4 col loads + 4 kv
// gathers issued before use -> 4x outstanding loads (was latency-bound).
// Output split to bf16 hi/lo (A-operand of the out-projection GEMM).
__global__ __launch_bounds__(256) void fused_agg(
    const int* __restrict__ rowptr, const unsigned int* __restrict__ col,
    const float* __restrict__ kqv, const float2* __restrict__ kv2,
    unsigned short* __restrict__ outh, unsigned short* __restrict__ outl,
    int nnodes)
{
    int task = blockIdx.x * 16 + (threadIdx.x >> 4);
    int f    = threadIdx.x & 15;
    if (task >= nnodes * 8) return;
    int dst = task >> 3, h = task & 7;
    const int foff = h * 16 + f;
    float q = kqv[(size_t)dst * 384 + 128 + foff];
    int i = rowptr[dst], end = rowptr[dst + 1];
    float s = 0.f, o = 0.f;
    for (; i + 4 <= end; i += 4) {
        unsigned int c0 = col[i],     c1 = col[i + 1];
        unsigned int c2 = col[i + 2], c3 = col[i + 3];
        float2 kv0 = kv2[(size_t)c0 * 128 + foff];
        float2 kv1 = kv2[(size_t)c1 * 128 + foff];
        float2 kv2v = kv2[(size_t)c2 * 128 + foff];
        float2 kv3 = kv2[(size_t)c3 * 128 + foff];
        float p0 = q * kv0.x, p1 = q * kv1.x, p2 = q * kv2v.x, p3 = q * kv3.x;
#pragma unroll
        for (int off = 1; off < 16; off <<= 1) {
            p0 += __shfl_xor(p0, off, 16);
            p1 += __shfl_xor(p1, off, 16);
            p2 += __shfl_xor(p2, off, 16);
            p3 += __shfl_xor(p3, off, 16);
        }
        float e0 = __expf(p0), e1 = __expf(p1), e2 = __expf(p2), e3 = __expf(p3);
        s += e0; o = fmaf(e0, kv0.y, o);
        s += e1; o = fmaf(e1, kv1.y, o);
        s += e2; o = fmaf(e2, kv2v.y, o);
        s += e3; o = fmaf(e3, kv3.y, o);
    }
    for (; i < end; ++i) {
        unsigned int cv = col[i];
        float2 kv = kv2[(size_t)cv * 128 + foff];
        float part = q * kv.x;
#pragma unroll
        for (int off = 1; off < 16; off <<= 1) part += __shfl_xor(part, off, 16);
        float ev = __expf(part);
        s += ev;
        o = fmaf(ev, kv.y, o);
    }
    float r = o / (s + 1e-16f);
    float gr = gelu_exact(r);
    unsigned short hh = f2bf(gr);
    size_t oidx = (size_t)dst * 128 + foff;
    outh[oidx] = hh;
    outl[oidx] = f2bf(gr - bf2f(hh));
}

// ---------------------------------------------------------------------------
extern "C" void kernel_launch(void* const* d_in, const int* in_sizes, int n_in,
                              void* d_out, int out_size, void* d_ws, size_t ws_size,
                              hipStream_t stream)
{
    const float* x     = (const float*)d_in[0];
    const int*   ef    = (const int*)d_in[1];
    const int*   eg    = (const int*)d_in[2];
    const float* kqv_w = (const float*)d_in[3];
    const float* kqv_b = (const float*)d_in[4];
    const float* a_f   = (const float*)d_in[5];
    const float* m_f   = (const float*)d_in[6];
    const float* p_f   = (const float*)d_in[7];
    const float* a_g   = (const float*)d_in[8];
    const float* m_g   = (const float*)d_in[9];
    const float* p_g   = (const float*)d_in[10];
    const float* out_w = (const float*)d_in[11];
    const float* out_b = (const float*)d_in[12];
    const float* skip  = (const float*)d_in[13];
    const float* ln1_g = (const float*)d_in[14];
    const float* ln1_b = (const float*)d_in[15];
    const float* ln2_g = (const float*)d_in[16];
    const float* ln2_b = (const float*)d_in[17];
    const float* w1    = (const float*)d_in[18];
    const float* b1    = (const float*)d_in[19];
    const float* w2    = (const float*)d_in[20];
    const float* b2    = (const float*)d_in[21];
    float* out = (float*)d_out;

    const int D  = 128;
    const int Nn = in_sizes[0] / D;   // 50000
    const int E1 = in_sizes[1] / 2;   // 300000
    const int E2 = in_sizes[2] / 2;   // 300000

    // ---- workspace (f32 units), ~9.16*ND = 234 MB:
    // [0,ND)      xn f32 (LN1 out; aux2 of out-proj)
    // [ND,4ND)    kqvb f32
    // [4ND,8ND)   kvF,kvG float2  -- overlaid by h1 bf16 hi/lo after fused_agg
    // [8ND,9ND)   xn bf16 hi/lo (LN1/LN2) -- overlaid by gagg bf16 between
    // [9ND,..)    weights bf16 (transposed), then ints (deg/rowptr/cursor/col)
    float* ws = (float*)d_ws;
    size_t ND = (size_t)Nn * D;
    float* xn   = ws;
    float* kqvb = xn + ND;
    float2* kvF = (float2*)(kqvb + 3 * ND);
    float2* kvG = kvF + ND;
    unsigned short* h1h = (unsigned short*)kvF;        // [Nn*512]
    unsigned short* h1l = h1h + (size_t)Nn * 512;
    unsigned short* abase = (unsigned short*)(ws + 8 * ND);
    unsigned short* xnh = abase;                       // [ND]
    unsigned short* xnl = abase + ND;
    unsigned short* ggh = abase;                       // overlay (disjoint life)
    unsigned short* ggl = abase + ND;
    unsigned short* kwh = (unsigned short*)(ws + 9 * ND);  // [384*128]
    unsigned short* kwl = kwh + 384 * 128;
    unsigned short* owh = kwl + 384 * 128;                 // [128*128]
    unsigned short* owl = owh + 128 * 128;
    unsigned short* w1h = owl + 128 * 128;                 // [512*128]
    unsigned short* w1l = w1h + 512 * 128;
    unsigned short* w2h = w1l + 512 * 128;                 // [128*512]
    unsigned short* w2l = w2h + 128 * 512;
    int* ibase  = (int*)(w2l + 128 * 512);
    int* deg    = ibase;
    int* rowptr = deg + Nn;
    int* cursor = rowptr + Nn + 1;
    unsigned int* col = (unsigned int*)(cursor + Nn);
    float* x1 = out;   // x1 staged in d_out

    const int ln_grid = (Nn + 3) / 4;
    const int mg = (Nn + 127) / 128;

    // 0. weight transpose+split (once per call; order independent)
    transpose_split_w<<<dim3(4, 12), 256, 0, stream>>>(kqv_w, kwh, kwl, 128, 384);
    transpose_split_w<<<dim3(4, 4),  256, 0, stream>>>(out_w, owh, owl, 128, 128);
    transpose_split_w<<<dim3(4, 16), 256, 0, stream>>>(w1,    w1h, w1l, 128, 512);
    transpose_split_w<<<dim3(16, 4), 256, 0, stream>>>(w2,    w2h, w2l, 512, 128);
    // 1. xn = LN1(x): f32 + bf16 split
    ln_kernel<<<ln_grid, 256, 0, stream>>>(x, ln1_g, ln1_b, xn, xnh, xnl, Nn);
    // 2. kqv = xn @ kqv_w + kqv_b (f32 out)
    gemm_bfp<0, 0><<<dim3(mg, 3), 256, 0, stream>>>(
        xnh, xnl, kwh, kwl, kqv_b, kqvb, nullptr, nullptr,
        Nn, 384, 128, nullptr, nullptr, nullptr);
    // 3. per-node relation transforms
    rel_transform<<<(Nn + 1) / 2, 256, 0, stream>>>(
        kqvb, a_f, m_f, a_g, m_g, p_f, p_g, kvF, kvG, Nn);
    // 4. CSR build
    zero_deg<<<(Nn + 255) / 256, 256, 0, stream>>>(deg, Nn);
    count_deg<<<(E1 + 255) / 256, 256, 0, stream>>>(ef, E1, deg);
    count_deg<<<(E2 + 255) / 256, 256, 0, stream>>>(eg, E2, deg);
    scan_kernel<<<1, 1024, 0, stream>>>(deg, rowptr, cursor, Nn);
    fill_csr<<<(E1 + 255) / 256, 256, 0, stream>>>(ef, E1, 0, cursor, col);
    fill_csr<<<(E2 + 255) / 256, 256, 0, stream>>>(eg, E2, Nn, cursor, col);
    // 5. fused agg -> gelu(agg) as bf16 split (gagg overlays xn bf16)
    fused_agg<<<(Nn * 8) / 16, 256, 0, stream>>>(
        rowptr, col, kqvb, kvF, ggh, ggl, Nn);
    // 6. x1 = x + sig*(gagg @ out_w + out_b) + (1-sig)*xn  (into d_out)
    gemm_bfp<2, 0><<<dim3(mg, 1), 256, 0, stream>>>(
        ggh, ggl, owh, owl, out_b, x1, nullptr, nullptr,
        Nn, 128, 128, x, xn, skip);
    // 7. xn2 = LN2(x1): bf16 split only (f32 not needed; reuses xn bf16 slots)
    ln_kernel<<<ln_grid, 256, 0, stream>>>(x1, ln2_g, ln2_b, nullptr, xnh, xnl, Nn);
    // 8. h1 = gelu(xn2 @ w1 + b1) -> bf16 split (overlays kvF/kvG)
    gemm_bfp<1, 1><<<dim3(mg, 4), 256, 0, stream>>>(
        xnh, xnl, w1h, w1l, b1, nullptr, h1h, h1l,
        Nn, 512, 128, nullptr, nullptr, nullptr);
    // 9. out = x1 + h1 @ w2 + b2
    gemm_bfp<3, 0><<<dim3(mg, 1), 256, 0, stream>>>(
        h1h, h1l, w2h, w2l, b2, out, nullptr, nullptr,
        Nn, 128, 512, x1, nullptr, nullptr);
}

// Round 13
// 578.854 us; speedup vs baseline: 1.5270x; 1.1705x over previous
//
#include <hip/hip_runtime.h>
#include <math.h>

// ---------------------------------------------------------------------------
// HGT transformer layer. N=50000, D=128, H=8, DH=16, E=300000 per edge type.
// R5:  CSR + fused online-softmax aggregation (5000 -> 872 us).
// R10: bf16x3 MFMA GEMMs (872 -> 744).
// R12: pre-split bf16 operands + 4-wide pipelined fused_agg (744 -> 677).
// R13: single-block serial scan was the TOP dispatch (109 us, 0.14% occ).
//      Replaced with 3-phase hierarchical scan (~15 us).
// ---------------------------------------------------------------------------

using bf16x8 = __attribute__((ext_vector_type(8))) short;
using us8    = __attribute__((ext_vector_type(8))) unsigned short;
using f32x4  = __attribute__((ext_vector_type(4))) float;

__device__ __forceinline__ float gelu_exact(float x) {
    return 0.5f * x * (1.0f + erff(x * 0.70710678118654752f));
}
__device__ __forceinline__ unsigned short f2bf(float x) {  // RNE float->bf16
    unsigned int u = __float_as_uint(x);
    u += 0x7fffu + ((u >> 16) & 1u);
    return (unsigned short)(u >> 16);
}
__device__ __forceinline__ float bf2f(unsigned short h) {
    return __uint_as_float(((unsigned int)h) << 16);
}

// --------------------------- LayerNorm (rows of 128) -----------------------
__global__ __launch_bounds__(256) void ln_kernel(
    const float* __restrict__ x, const float* __restrict__ g,
    const float* __restrict__ b, float* __restrict__ outf,
    unsigned short* __restrict__ outh, unsigned short* __restrict__ outl,
    int nrows)
{
    int row  = (int)((blockIdx.x * 256 + threadIdx.x) >> 6);
    int lane = threadIdx.x & 63;
    if (row >= nrows) return;
    float2 xv = *(const float2*)&x[(size_t)row * 128 + lane * 2];
    float s = xv.x + xv.y;
#pragma unroll
    for (int off = 32; off >= 1; off >>= 1) s += __shfl_xor(s, off, 64);
    float mu = s * (1.0f / 128.0f);
    float d0 = xv.x - mu, d1 = xv.y - mu;
    float v = d0 * d0 + d1 * d1;
#pragma unroll
    for (int off = 32; off >= 1; off >>= 1) v += __shfl_xor(v, off, 64);
    float rs = rsqrtf(v * (1.0f / 128.0f) + 1e-5f);
    float2 gv = *(const float2*)&g[lane * 2];
    float2 bv = *(const float2*)&b[lane * 2];
    float o0 = d0 * rs * gv.x + bv.x;
    float o1 = d1 * rs * gv.y + bv.y;
    size_t idx = (size_t)row * 128 + lane * 2;
    if (outf) *(float2*)&outf[idx] = make_float2(o0, o1);
    unsigned short h0 = f2bf(o0), h1 = f2bf(o1);
    *(ushort2*)&outh[idx] = make_ushort2(h0, h1);
    *(ushort2*)&outl[idx] = make_ushort2(f2bf(o0 - bf2f(h0)), f2bf(o1 - bf2f(h1)));
}

// ------------- weight transpose + bf16 hi/lo split (once per call) ---------
__global__ __launch_bounds__(256) void transpose_split_w(
    const float* __restrict__ W, unsigned short* __restrict__ Wh,
    unsigned short* __restrict__ Wl, int K, int N)
{
    __shared__ unsigned short th[32][33], tl[32][33];
    int kt = blockIdx.x * 32, nt = blockIdx.y * 32;
    int tx = threadIdx.x & 31, ty = threadIdx.x >> 5;
#pragma unroll
    for (int j = 0; j < 32; j += 8) {
        float v = W[(size_t)(kt + ty + j) * N + nt + tx];
        unsigned short h = f2bf(v);
        th[ty + j][tx] = h;
        tl[ty + j][tx] = f2bf(v - bf2f(h));
    }
    __syncthreads();
#pragma unroll
    for (int j = 0; j < 32; j += 8) {
        size_t o = (size_t)(nt + ty + j) * K + kt + tx;
        Wh[o] = th[tx][ty + j];
        Wl[o] = tl[tx][ty + j];
    }
}

// ---------------- bf16x3 MFMA GEMM, pre-split operands ---------------------
template <int EPI, int OBF>
__global__ __launch_bounds__(256) void gemm_bfp(
    const unsigned short* __restrict__ Ah, const unsigned short* __restrict__ Al,
    const unsigned short* __restrict__ Bh, const unsigned short* __restrict__ Bl,
    const float* __restrict__ bias, float* __restrict__ C,
    unsigned short* __restrict__ Ch, unsigned short* __restrict__ Cl,
    int M, int N, int K,
    const float* __restrict__ aux1, const float* __restrict__ aux2,
    const float* __restrict__ skipp)
{
    __shared__ __align__(16) unsigned short sAh[128 * 40], sAl[128 * 40];
    __shared__ __align__(16) unsigned short sBh[128 * 40], sBl[128 * 40];
    const int t    = threadIdx.x;
    const int bm   = blockIdx.x * 128;
    const int bn   = blockIdx.y * 128;
    const int lane = t & 63;
    const int wave = t >> 6;
    const int wm   = (wave >> 1) * 64;
    const int wn   = (wave & 1) * 64;
    const int lrow = lane & 15;
    const int lkg  = lane >> 4;

    const int s_rc = t >> 1;
    const int s_kc = (t & 1) * 16;

    f32x4 acc[4][4] = {};

    for (int k0 = 0; k0 < K; k0 += 32) {
        {
            size_t ga = (size_t)(bm + s_rc) * K + k0 + s_kc;
            size_t gb = (size_t)(bn + s_rc) * K + k0 + s_kc;
            int ld = s_rc * 40 + s_kc;
            *(us8*)&sAh[ld]     = *(const us8*)&Ah[ga];
            *(us8*)&sAh[ld + 8] = *(const us8*)&Ah[ga + 8];
            *(us8*)&sAl[ld]     = *(const us8*)&Al[ga];
            *(us8*)&sAl[ld + 8] = *(const us8*)&Al[ga + 8];
            *(us8*)&sBh[ld]     = *(const us8*)&Bh[gb];
            *(us8*)&sBh[ld + 8] = *(const us8*)&Bh[gb + 8];
            *(us8*)&sBl[ld]     = *(const us8*)&Bl[gb];
            *(us8*)&sBl[ld + 8] = *(const us8*)&Bl[gb + 8];
        }
        __syncthreads();

        bf16x8 ah[4], al[4];
#pragma unroll
        for (int mi = 0; mi < 4; ++mi) {
            int r = wm + mi * 16 + lrow;
            ah[mi] = *(const bf16x8*)&sAh[r * 40 + lkg * 8];
            al[mi] = *(const bf16x8*)&sAl[r * 40 + lkg * 8];
        }
#pragma unroll
        for (int ni = 0; ni < 4; ++ni) {
            int c = wn + ni * 16 + lrow;
            bf16x8 bh = *(const bf16x8*)&sBh[c * 40 + lkg * 8];
            bf16x8 bl = *(const bf16x8*)&sBl[c * 40 + lkg * 8];
#pragma unroll
            for (int mi = 0; mi < 4; ++mi) {
                acc[mi][ni] = __builtin_amdgcn_mfma_f32_16x16x32_bf16(ah[mi], bh, acc[mi][ni], 0, 0, 0);
                acc[mi][ni] = __builtin_amdgcn_mfma_f32_16x16x32_bf16(ah[mi], bl, acc[mi][ni], 0, 0, 0);
                acc[mi][ni] = __builtin_amdgcn_mfma_f32_16x16x32_bf16(al[mi], bh, acc[mi][ni], 0, 0, 0);
            }
        }
        __syncthreads();
    }

    float sgk = 0.0f;
    if (EPI == 2) sgk = 1.0f / (1.0f + expf(-skipp[0]));
#pragma unroll
    for (int mi = 0; mi < 4; ++mi) {
#pragma unroll
        for (int r4 = 0; r4 < 4; ++r4) {
            int row = bm + wm + mi * 16 + lkg * 4 + r4;
            if (row >= M) continue;
#pragma unroll
            for (int ni = 0; ni < 4; ++ni) {
                int col = bn + wn + ni * 16 + lrow;
                size_t cidx = (size_t)row * N + col;
                float v = acc[mi][ni][r4] + bias[col];
                if (EPI == 1) v = gelu_exact(v);
                if (EPI == 2) v = aux1[cidx] + sgk * v + (1.0f - sgk) * aux2[cidx];
                if (EPI == 3) v = aux1[cidx] + v;
                if (OBF) {
                    unsigned short h = f2bf(v);
                    Ch[cidx] = h;
                    Cl[cidx] = f2bf(v - bf2f(h));
                } else {
                    C[cidx] = v;
                }
            }
        }
    }
}

// ------------------- per-node relation transforms --------------------------
__global__ __launch_bounds__(256) void rel_transform(
    const float* __restrict__ kqv,
    const float* __restrict__ a_f, const float* __restrict__ m_f,
    const float* __restrict__ a_g, const float* __restrict__ m_g,
    const float* __restrict__ p_f, const float* __restrict__ p_g,
    float2* __restrict__ kvF, float2* __restrict__ kvG, int nnodes)
{
    __shared__ float sAf[8 * 16 * 17], sMf[8 * 16 * 17];
    __shared__ float sAg[8 * 16 * 17], sMg[8 * 16 * 17];
    for (int i = threadIdx.x; i < 2048; i += 256) {
        int o = (i >> 4) * 17 + (i & 15);
        sAf[o] = a_f[i]; sMf[o] = m_f[i];
        sAg[o] = a_g[i]; sMg[o] = m_g[i];
    }
    __syncthreads();
    int t = threadIdx.x;
    int f = t & 15, h = (t >> 4) & 7, nl = t >> 7;
    int n = blockIdx.x * 2 + nl;
    if (n >= nnodes) return;
    const float* kp = &kqv[(size_t)n * 384 + h * 16];
    const float* vp = kp + 256;
    float kd[16], vd[16];
#pragma unroll
    for (int i4 = 0; i4 < 4; ++i4) {
        float4 k4 = *(const float4*)&kp[i4 * 4];
        float4 v4 = *(const float4*)&vp[i4 * 4];
        kd[i4 * 4 + 0] = k4.x; kd[i4 * 4 + 1] = k4.y;
        kd[i4 * 4 + 2] = k4.z; kd[i4 * 4 + 3] = k4.w;
        vd[i4 * 4 + 0] = v4.x; vd[i4 * 4 + 1] = v4.y;
        vd[i4 * 4 + 2] = v4.z; vd[i4 * 4 + 3] = v4.w;
    }
    float rkf = 0.f, rkg = 0.f, rvf = 0.f, rvg = 0.f;
#pragma unroll
    for (int d = 0; d < 16; ++d) {
        int idx = (h * 16 + d) * 17 + f;
        rkf += kd[d] * sAf[idx];
        rkg += kd[d] * sAg[idx];
        rvf += vd[d] * sMf[idx];
        rvg += vd[d] * sMg[idx];
    }
    float cf = p_f[h] * 0.25f;
    float cg = p_g[h] * 0.25f;
    size_t o = (size_t)n * 128 + h * 16 + f;
    kvF[o] = make_float2(rkf * cf, rvf);
    kvG[o] = make_float2(rkg * cg, rvg);
}

// -------------------- CSR build ---------------------------------------------
__global__ __launch_bounds__(256) void zero_deg(int* __restrict__ deg, int n) {
    int i = blockIdx.x * 256 + threadIdx.x;
    if (i < n) deg[i] = 0;
}

__global__ __launch_bounds__(256) void count_deg(
    const int* __restrict__ edge, int E, int* __restrict__ deg)
{
    int e = blockIdx.x * 256 + threadIdx.x;
    if (e >= E) return;
    atomicAdd(&deg[edge[E + e]], 1);
}

// 3-phase hierarchical exclusive scan (replaces 109us single-block scan):
// A: per-block (256 elems) reduce -> bsum;  B: 1-block scan of bsum (nb<=256);
// C: per-block LDS scan + bsum offset -> rowptr/cursor, last elem -> rowptr[n].
__global__ __launch_bounds__(256) void scan_phaseA(
    const int* __restrict__ deg, int* __restrict__ bsum, int n)
{
    __shared__ int sm[256];
    int i = blockIdx.x * 256 + threadIdx.x;
    sm[threadIdx.x] = (i < n) ? deg[i] : 0;
    __syncthreads();
    for (int off = 128; off >= 1; off >>= 1) {
        if (threadIdx.x < off) sm[threadIdx.x] += sm[threadIdx.x + off];
        __syncthreads();
    }
    if (threadIdx.x == 0) bsum[blockIdx.x] = sm[0];
}

__global__ __launch_bounds__(256) void scan_phaseB(
    const int* __restrict__ bsum, int* __restrict__ boff, int nb)
{
    __shared__ int sm[256];
    int v = (threadIdx.x < nb) ? bsum[threadIdx.x] : 0;
    sm[threadIdx.x] = v;
    __syncthreads();
    for (int off = 1; off < 256; off <<= 1) {
        int tv = (threadIdx.x >= off) ? sm[threadIdx.x - off] : 0;
        __syncthreads();
        sm[threadIdx.x] += tv;
        __syncthreads();
    }
    if (threadIdx.x < nb) boff[threadIdx.x] = sm[threadIdx.x] - v;  // exclusive
}

__global__ __launch_bounds__(256) void scan_phaseC(
    const int* __restrict__ deg, const int* __restrict__ boff,
    int* __restrict__ rowptr, int* __restrict__ cursor, int n)
{
    __shared__ int sm[256];
    int i = blockIdx.x * 256 + threadIdx.x;
    int v = (i < n) ? deg[i] : 0;
    sm[threadIdx.x] = v;
    __syncthreads();
    for (int off = 1; off < 256; off <<= 1) {
        int tv = (threadIdx.x >= off) ? sm[threadIdx.x - off] : 0;
        __syncthreads();
        sm[threadIdx.x] += tv;
        __syncthreads();
    }
    int incl = sm[threadIdx.x];
    int base = boff[blockIdx.x];
    if (i < n) {
        int e = base + incl - v;
        rowptr[i] = e;
        cursor[i] = e;
        if (i == n - 1) rowptr[n] = base + incl;
    }
}

__global__ __launch_bounds__(256) void fill_csr(
    const int* __restrict__ edge, int E, int addbase,
    int* __restrict__ cursor, unsigned int* __restrict__ col)
{
    int e = blockIdx.x * 256 + threadIdx.x;
    if (e >= E) return;
    int src = edge[e], dst = edge[E + e];
    int pos = atomicAdd(&cursor[dst], 1);
    col[pos] = (unsigned int)(src + addbase);
}

// -------------- fused gather + softmax + gelu (4-wide pipelined) -----------
__global__ __launch_bounds__(256) void fused_agg(
    const int* __restrict__ rowptr, const unsigned int* __restrict__ col,
    const float* __restrict__ kqv, const float2* __restrict__ kv2,
    unsigned short* __restrict__ outh, unsigned short* __restrict__ outl,
    int nnodes)
{
    int task = blockIdx.x * 16 + (threadIdx.x >> 4);
    int f    = threadIdx.x & 15;
    if (task >= nnodes * 8) return;
    int dst = task >> 3, h = task & 7;
    const int foff = h * 16 + f;
    float q = kqv[(size_t)dst * 384 + 128 + foff];
    int i = rowptr[dst], end = rowptr[dst + 1];
    float s = 0.f, o = 0.f;
    for (; i + 4 <= end; i += 4) {
        unsigned int c0 = col[i],     c1 = col[i + 1];
        unsigned int c2 = col[i + 2], c3 = col[i + 3];
        float2 kv0 = kv2[(size_t)c0 * 128 + foff];
        float2 kv1 = kv2[(size_t)c1 * 128 + foff];
        float2 kv2v = kv2[(size_t)c2 * 128 + foff];
        float2 kv3 = kv2[(size_t)c3 * 128 + foff];
        float p0 = q * kv0.x, p1 = q * kv1.x, p2 = q * kv2v.x, p3 = q * kv3.x;
#pragma unroll
        for (int off = 1; off < 16; off <<= 1) {
            p0 += __shfl_xor(p0, off, 16);
            p1 += __shfl_xor(p1, off, 16);
            p2 += __shfl_xor(p2, off, 16);
            p3 += __shfl_xor(p3, off, 16);
        }
        float e0 = __expf(p0), e1 = __expf(p1), e2 = __expf(p2), e3 = __expf(p3);
        s += e0; o = fmaf(e0, kv0.y, o);
        s += e1; o = fmaf(e1, kv1.y, o);
        s += e2; o = fmaf(e2, kv2v.y, o);
        s += e3; o = fmaf(e3, kv3.y, o);
    }
    for (; i < end; ++i) {
        unsigned int cv = col[i];
        float2 kv = kv2[(size_t)cv * 128 + foff];
        float part = q * kv.x;
#pragma unroll
        for (int off = 1; off < 16; off <<= 1) part += __shfl_xor(part, off, 16);
        float ev = __expf(part);
        s += ev;
        o = fmaf(ev, kv.y, o);
    }
    float r = o / (s + 1e-16f);
    float gr = gelu_exact(r);
    unsigned short hh = f2bf(gr);
    size_t oidx = (size_t)dst * 128 + foff;
    outh[oidx] = hh;
    outl[oidx] = f2bf(gr - bf2f(hh));
}

// ---------------------------------------------------------------------------
extern "C" void kernel_launch(void* const* d_in, const int* in_sizes, int n_in,
                              void* d_out, int out_size, void* d_ws, size_t ws_size,
                              hipStream_t stream)
{
    const float* x     = (const float*)d_in[0];
    const int*   ef    = (const int*)d_in[1];
    const int*   eg    = (const int*)d_in[2];
    const float* kqv_w = (const float*)d_in[3];
    const float* kqv_b = (const float*)d_in[4];
    const float* a_f   = (const float*)d_in[5];
    const float* m_f   = (const float*)d_in[6];
    const float* p_f   = (const float*)d_in[7];
    const float* a_g   = (const float*)d_in[8];
    const float* m_g   = (const float*)d_in[9];
    const float* p_g   = (const float*)d_in[10];
    const float* out_w = (const float*)d_in[11];
    const float* out_b = (const float*)d_in[12];
    const float* skip  = (const float*)d_in[13];
    const float* ln1_g = (const float*)d_in[14];
    const float* ln1_b = (const float*)d_in[15];
    const float* ln2_g = (const float*)d_in[16];
    const float* ln2_b = (const float*)d_in[17];
    const float* w1    = (const float*)d_in[18];
    const float* b1    = (const float*)d_in[19];
    const float* w2    = (const float*)d_in[20];
    const float* b2    = (const float*)d_in[21];
    float* out = (float*)d_out;

    const int D  = 128;
    const int Nn = in_sizes[0] / D;   // 50000
    const int E1 = in_sizes[1] / 2;   // 300000
    const int E2 = in_sizes[2] / 2;   // 300000
    const int nb = (Nn + 255) / 256;  // scan blocks (196 <= 256)

    // ---- workspace layout (as R12) + bsum/boff ints.
    float* ws = (float*)d_ws;
    size_t ND = (size_t)Nn * D;
    float* xn   = ws;
    float* kqvb = xn + ND;
    float2* kvF = (float2*)(kqvb + 3 * ND);
    float2* kvG = kvF + ND;
    unsigned short* h1h = (unsigned short*)kvF;        // [Nn*512]
    unsigned short* h1l = h1h + (size_t)Nn * 512;
    unsigned short* abase = (unsigned short*)(ws + 8 * ND);
    unsigned short* xnh = abase;                       // [ND]
    unsigned short* xnl = abase + ND;
    unsigned short* ggh = abase;                       // overlay (disjoint life)
    unsigned short* ggl = abase + ND;
    unsigned short* kwh = (unsigned short*)(ws + 9 * ND);  // [384*128]
    unsigned short* kwl = kwh + 384 * 128;
    unsigned short* owh = kwl + 384 * 128;                 // [128*128]
    unsigned short* owl = owh + 128 * 128;
    unsigned short* w1h = owl + 128 * 128;                 // [512*128]
    unsigned short* w1l = w1h + 512 * 128;
    unsigned short* w2h = w1l + 512 * 128;                 // [128*512]
    unsigned short* w2l = w2h + 128 * 512;
    int* ibase  = (int*)(w2l + 128 * 512);
    int* deg    = ibase;
    int* rowptr = deg + Nn;
    int* cursor = rowptr + Nn + 1;
    int* bsum   = cursor + Nn;
    int* boff   = bsum + nb;
    unsigned int* col = (unsigned int*)(boff + nb);
    float* x1 = out;   // x1 staged in d_out

    const int ln_grid = (Nn + 3) / 4;
    const int mg = (Nn + 127) / 128;

    // 0. weight transpose+split (once per call; order independent)
    transpose_split_w<<<dim3(4, 12), 256, 0, stream>>>(kqv_w, kwh, kwl, 128, 384);
    transpose_split_w<<<dim3(4, 4),  256, 0, stream>>>(out_w, owh, owl, 128, 128);
    transpose_split_w<<<dim3(4, 16), 256, 0, stream>>>(w1,    w1h, w1l, 128, 512);
    transpose_split_w<<<dim3(16, 4), 256, 0, stream>>>(w2,    w2h, w2l, 512, 128);
    // 1. xn = LN1(x): f32 + bf16 split
    ln_kernel<<<ln_grid, 256, 0, stream>>>(x, ln1_g, ln1_b, xn, xnh, xnl, Nn);
    // 2. kqv = xn @ kqv_w + kqv_b (f32 out)
    gemm_bfp<0, 0><<<dim3(mg, 3), 256, 0, stream>>>(
        xnh, xnl, kwh, kwl, kqv_b, kqvb, nullptr, nullptr,
        Nn, 384, 128, nullptr, nullptr, nullptr);
    // 3. per-node relation transforms
    rel_transform<<<(Nn + 1) / 2, 256, 0, stream>>>(
        kqvb, a_f, m_f, a_g, m_g, p_f, p_g, kvF, kvG, Nn);
    // 4. CSR build (hierarchical scan)
    zero_deg<<<nb, 256, 0, stream>>>(deg, Nn);
    count_deg<<<(E1 + 255) / 256, 256, 0, stream>>>(ef, E1, deg);
    count_deg<<<(E2 + 255) / 256, 256, 0, stream>>>(eg, E2, deg);
    scan_phaseA<<<nb, 256, 0, stream>>>(deg, bsum, Nn);
    scan_phaseB<<<1, 256, 0, stream>>>(bsum, boff, nb);
    scan_phaseC<<<nb, 256, 0, stream>>>(deg, boff, rowptr, cursor, Nn);
    fill_csr<<<(E1 + 255) / 256, 256, 0, stream>>>(ef, E1, 0, cursor, col);
    fill_csr<<<(E2 + 255) / 256, 256, 0, stream>>>(eg, E2, Nn, cursor, col);
    // 5. fused agg -> gelu(agg) as bf16 split (gagg overlays xn bf16)
    fused_agg<<<(Nn * 8) / 16, 256, 0, stream>>>(
        rowptr, col, kqvb, kvF, ggh, ggl, Nn);
    // 6. x1 = x + sig*(gagg @ out_w + out_b) + (1-sig)*xn  (into d_out)
    gemm_bfp<2, 0><<<dim3(mg, 1), 256, 0, stream>>>(
        ggh, ggl, owh, owl, out_b, x1, nullptr, nullptr,
        Nn, 128, 128, x, xn, skip);
    // 7. xn2 = LN2(x1): bf16 split only (reuses xn bf16 slots)
    ln_kernel<<<ln_grid, 256, 0, stream>>>(x1, ln2_g, ln2_b, nullptr, xnh, xnl, Nn);
    // 8. h1 = gelu(xn2 @ w1 + b1) -> bf16 split (overlays kvF/kvG)
    gemm_bfp<1, 1><<<dim3(mg, 4), 256, 0, stream>>>(
        xnh, xnl, w1h, w1l, b1, nullptr, h1h, h1l,
        Nn, 512, 128, nullptr, nullptr, nullptr);
    // 9. out = x1 + h1 @ w2 + b2
    gemm_bfp<3, 0><<<dim3(mg, 1), 256, 0, stream>>>(
        h1h, h1l, w2h, w2l, b2, out, nullptr, nullptr,
        Nn, 128, 512, x1, nullptr, nullptr);
}